// Round 23
// baseline (752.052 us; speedup 1.0000x reference)
//
#include <hip/hip_runtime.h>
#include <math.h>

// Problem constants
constexpr int B  = 128;
constexpr int T  = 1024;
constexpr int IN_DIM = 32;
constexpr int D  = 128;
constexpr int H  = 8;
constexpr int DH = 16;   // D/H
constexpr int L  = 2;
constexpr int U  = 34;   // int(5*ln(1025))
constexpr int FF = 512;  // 4*D

typedef __attribute__((ext_vector_type(8))) _Float16 f16x8;
typedef __attribute__((ext_vector_type(2))) _Float16 h2;
typedef __attribute__((ext_vector_type(4))) float f32x4;

__device__ __forceinline__ unsigned short f2h(float x) {
  union { _Float16 h; unsigned short u; } v;
  v.h = (_Float16)x;
  return v.u;
}

__device__ __forceinline__ h2 shfl_xor_h2(h2 v, int off) {
  union { h2 h; int i; } u;
  u.h = v;
  u.i = __shfl_xor(u.i, off);
  return u.h;
}

// Branch-free erf, Abramowitz-Stegun 7.1.26 (|err| <= 1.5e-7)  (R10-verified)
__device__ __forceinline__ float erf_fast(float x) {
  float a = fabsf(x);
  float t = __builtin_amdgcn_rcpf(fmaf(0.3275911f, a, 1.f));
  float y = t * (0.254829592f +
            t * (-0.284496736f +
            t * (1.421413741f +
            t * (-1.453152027f +
            t * 1.061405429f))));
  float r = 1.f - y * __expf(-a * a);
  return copysignf(r, x);
}

// ---------------- helpers ----------------

// Paired block reductions (one barrier pair for two values)  (R15-verified)
__device__ __forceinline__ void blockMax2(float& a, float& b, float* red) {
  for (int off = 32; off; off >>= 1) {
    a = fmaxf(a, __shfl_down(a, off));
    b = fmaxf(b, __shfl_down(b, off));
  }
  if ((threadIdx.x & 63) == 0) {
    red[threadIdx.x >> 6] = a;
    red[4 + (threadIdx.x >> 6)] = b;
  }
  __syncthreads();
  a = fmaxf(fmaxf(red[0], red[1]), fmaxf(red[2], red[3]));
  b = fmaxf(fmaxf(red[4], red[5]), fmaxf(red[6], red[7]));
  __syncthreads();
}

__device__ __forceinline__ void blockSum2(float& a, float& b, float* red) {
  for (int off = 32; off; off >>= 1) {
    a += __shfl_down(a, off);
    b += __shfl_down(b, off);
  }
  if ((threadIdx.x & 63) == 0) {
    red[threadIdx.x >> 6] = a;
    red[4 + (threadIdx.x >> 6)] = b;
  }
  __syncthreads();
  a = red[0] + red[1] + red[2] + red[3];
  b = red[4] + red[5] + red[6] + red[7];
  __syncthreads();
}

// ---------------- kernels ----------------

// All-weights transpose+f16 for one layer. 163840 elements -> 640 blocks x 256.
__global__ void k_prep_all(const float* __restrict__ wk_l,
                           const float* __restrict__ wv_l,
                           const float* __restrict__ w1_l,   // [128][512]
                           const float* __restrict__ w2_l,   // [512][128]
                           unsigned short* __restrict__ wkT,
                           unsigned short* __restrict__ wvT,
                           unsigned short* __restrict__ w1T,
                           unsigned short* __restrict__ w2T) {
  int idx = blockIdx.x * 256 + threadIdx.x;
  if (idx < 16384) {
    int n = idx >> 7, k = idx & 127;
    wkT[idx] = f2h(wk_l[k * 128 + n]);
  } else if (idx < 32768) {
    int j = idx - 16384;
    int n = j >> 7, k = j & 127;
    wvT[j] = f2h(wv_l[k * 128 + n]);
  } else if (idx < 98304) {
    int j = idx - 32768;                 // out[n*128+k], n<512, k<128
    int n = j >> 7, k = j & 127;
    w1T[j] = f2h(w1_l[k * 512 + n]);
  } else if (idx < 163840) {
    int j = idx - 98304;                 // out[n*512+k], n<128, k<512
    int n = j >> 9, k = j & 511;
    w2T[j] = f2h(w2_l[k * 128 + n]);
  }
}

// h[b,t,:] = x[b,t,:] @ proj_w + proj_b + pos_enc(t,:)
__global__ __launch_bounds__(D) void k_proj(const float* __restrict__ x,
                                            const float* __restrict__ pw,
                                            const float* __restrict__ pb,
                                            float* __restrict__ h) {
  int row = blockIdx.x;            // b*T + t
  int t = row & (T - 1);
  int d = threadIdx.x;
  __shared__ float xs[IN_DIM];
  if (threadIdx.x < IN_DIM) xs[threadIdx.x] = x[(size_t)row * IN_DIM + threadIdx.x];
  __syncthreads();
  float acc = pb[d];
#pragma unroll
  for (int i = 0; i < IN_DIM; ++i) acc += xs[i] * pw[i * D + d];
  int j = d >> 1;
  float div = __expf((float)(2 * j) * (-logf(10000.f) / (float)D));
  float ang = (float)t * div;
  acc += (d & 1) ? __cosf(ang) : __sinf(ang);
  h[(size_t)row * D + d] = acc;
}

// Fused K,V projection via MFMA -> head-major f16 [B][H][T][DH]. (R8-verified)
__global__ __launch_bounds__(256) void k_kv_mfma2(
    const float* __restrict__ h,
    const unsigned short* __restrict__ wkt,   // [128][128] f16 (n-major)
    const unsigned short* __restrict__ wvt,
    unsigned short* __restrict__ kbuf, unsigned short* __restrict__ vbuf) {
  __shared__ unsigned short hsb[16 * 128];    // XOR-swizzled f16 (R5-verified)
  const int tid = threadIdx.x;
  const int r0 = blockIdx.x * 16;
  {
    int m = tid >> 4, kc = tid & 15;
    const float* src = h + (size_t)(r0 + m) * D + kc * 8;
    float4 x0 = *(const float4*)src;
    float4 x1 = *(const float4*)(src + 4);
    f16x8 p;
    p[0] = (_Float16)x0.x; p[1] = (_Float16)x0.y;
    p[2] = (_Float16)x0.z; p[3] = (_Float16)x0.w;
    p[4] = (_Float16)x1.x; p[5] = (_Float16)x1.y;
    p[6] = (_Float16)x1.z; p[7] = (_Float16)x1.w;
    int byte = (m << 8) + (kc << 4);
    byte ^= (m & 7) << 4;
    *(f16x8*)((char*)hsb + byte) = p;
  }
  __syncthreads();
  const int wv = tid >> 6;
  const int l15 = tid & 15;
  const int lq = (tid & 63) >> 4;
  f16x8 afr[4];
#pragma unroll
  for (int ks = 0; ks < 4; ++ks) {
    int byte = (l15 << 8) + ks * 64 + (lq << 4);
    byte ^= (l15 & 7) << 4;
    afr[ks] = *(const f16x8*)((const char*)hsb + byte);
  }
  const unsigned short* wt = (wv < 2) ? wkt : wvt;
  unsigned short* outp = (wv < 2) ? kbuf : vbuf;
  const int cw = (wv & 1) * 64;
  f32x4 acc[4];
#pragma unroll
  for (int nt = 0; nt < 4; ++nt) acc[nt] = (f32x4){0.f, 0.f, 0.f, 0.f};
#pragma unroll
  for (int nt = 0; nt < 4; ++nt) {
    const unsigned short* wp = wt + (size_t)(cw + nt * 16 + l15) * 128 + lq * 8;
#pragma unroll
    for (int ks = 0; ks < 4; ++ks) {
      f16x8 bf = *(const f16x8*)(wp + ks * 32);
      acc[nt] = __builtin_amdgcn_mfma_f32_16x16x32_f16(afr[ks], bf, acc[nt], 0, 0, 0);
    }
  }
#pragma unroll
  for (int nt = 0; nt < 4; ++nt) {
    int col = cw + nt * 16 + l15;
    int hcol = col >> 4, dh = col & 15;
#pragma unroll
    for (int r = 0; r < 4; ++r) {
      int row = r0 + 4 * lq + r;             // C/D: row = 4*(lane>>4)+reg
      int b = row >> 10, t = row & (T - 1);
      outp[(((size_t)b * H + hcol) * T + t) * DH + dh] = f2h(acc[nt][r]);
    }
  }
}

// Attention v9: attn8 + fused q computation (k_qrow eliminated).
// grid = B*H*17, block = 256.
__global__ __launch_bounds__(256) void k_attn9(const float* __restrict__ h,
                                               const int* __restrict__ idxl,
                                               const float* __restrict__ wq,
                                               const unsigned short* __restrict__ kbuf,
                                               const unsigned short* __restrict__ vbuf,
                                               float* __restrict__ ctx) {
  constexpr int NWG = B * H * 17;
  int bid = blockIdx.x;
  int orig = (bid & 7) * (NWG / 8) + (bid >> 3);   // bijective XCD chunk (R9-verified)
  int up = orig % 17;
  int gb = orig / 17;
  int hh = gb & 7, b = gb >> 3;
  int u0 = up * 2;                                 // u0+1 <= 33 < U always

  __shared__ float hs2[2][D];
  __shared__ float qf[2][DH];
  __shared__ float red[8];
  __shared__ float redw[4][2][DH];
  const int tid = threadIdx.x;

  // stage the two h rows
  {
    int uu = tid >> 7, k = tid & 127;
    int t = idxl[u0 + uu];
    hs2[uu][k] = h[((size_t)b * T + t) * D + k];
  }
  __syncthreads();
  // q slice: q[uu][dd] = sum_k hs2[uu][k] * wq[k][hh*16+dd]; 8 threads per output
  {
    int kk = tid & 7, dd = (tid >> 3) & 15, uu = tid >> 7;
    const float* hr = hs2[uu];
    const float* wqc = wq + hh * DH + dd;
    float s = 0.f;
#pragma unroll
    for (int k2 = 0; k2 < 16; ++k2) {
      int k = kk * 16 + k2;
      s += hr[k] * wqc[(size_t)k * D];
    }
#pragma unroll
    for (int off = 4; off; off >>= 1) s += __shfl_down(s, off, 8);
    if (kk == 0) qf[uu][dd] = s;
  }
  __syncthreads();

  h2 q0[8], q1[8];
#pragma unroll
  for (int j = 0; j < 8; ++j) {
    q0[j] = (h2){(_Float16)qf[0][2 * j], (_Float16)qf[0][2 * j + 1]};
    q1[j] = (h2){(_Float16)qf[1][2 * j], (_Float16)qf[1][2 * j + 1]};
  }
  const unsigned short* kg = kbuf + (size_t)gb * T * DH;
  const unsigned short* vg = vbuf + (size_t)gb * T * DH;

  // QK: scores stay in registers (4 t-steps per thread per u)  (R22-verified)
  float sc0[4], sc1[4];
  float lmax0 = -1e30f, lmax1 = -1e30f;
#pragma unroll
  for (int p = 0; p < 4; ++p) {
    int t = p * 256 + tid;
    const h2* k2 = (const h2*)(kg + t * DH);
    float s0 = 0.f, s1 = 0.f;
#pragma unroll
    for (int j = 0; j < 8; ++j) {
      h2 kv = k2[j];
      s0 = __builtin_amdgcn_fdot2(q0[j], kv, s0, false);
      s1 = __builtin_amdgcn_fdot2(q1[j], kv, s1, false);
    }
    s0 *= 0.25f; s1 *= 0.25f;        // 1/sqrt(16)
    sc0[p] = s0; sc1[p] = s1;
    lmax0 = fmaxf(lmax0, s0);
    lmax1 = fmaxf(lmax1, s1);
  }
  blockMax2(lmax0, lmax1, red);
  float lsum0 = 0.f, lsum1 = 0.f;
#pragma unroll
  for (int p = 0; p < 4; ++p) {
    sc0[p] = __expf(sc0[p] - lmax0);
    sc1[p] = __expf(sc1[p] - lmax1);
    lsum0 += sc0[p];
    lsum1 += sc1[p];
  }
  blockSum2(lsum0, lsum1, red);
  float inv0 = 1.f / lsum0;
  float inv1 = 1.f / lsum1;

  h2 p0[8], p1[8];
#pragma unroll
  for (int j = 0; j < 8; ++j) { p0[j] = (h2){0, 0}; p1[j] = (h2){0, 0}; }
#pragma unroll
  for (int p = 0; p < 4; ++p) {
    int t = p * 256 + tid;
    const h2* v2 = (const h2*)(vg + t * DH);
    _Float16 a0 = (_Float16)sc0[p], a1 = (_Float16)sc1[p];
    h2 a0h = (h2){a0, a0}, a1h = (h2){a1, a1};
#pragma unroll
    for (int j = 0; j < 8; ++j) {
      h2 vv = v2[j];
      p0[j] += a0h * vv;
      p1[j] += a1h * vv;
    }
  }
#pragma unroll
  for (int j = 0; j < 8; ++j) {
#pragma unroll
    for (int off = 32; off; off >>= 1) {
      p0[j] += shfl_xor_h2(p0[j], off);
      p1[j] += shfl_xor_h2(p1[j], off);
    }
  }
  const int wv = tid >> 6, lane = tid & 63;
  if (lane == 0) {
#pragma unroll
    for (int j = 0; j < 8; ++j) {
      redw[wv][0][2 * j]     = (float)p0[j][0];
      redw[wv][0][2 * j + 1] = (float)p0[j][1];
      redw[wv][1][2 * j]     = (float)p1[j][0];
      redw[wv][1][2 * j + 1] = (float)p1[j][1];
    }
  }
  __syncthreads();
  if (tid < 32) {
    int uu = tid >> 4, dh = tid & 15;
    float tot = redw[0][uu][dh] + redw[1][uu][dh] + redw[2][uu][dh] + redw[3][uu][dh];
    float inv = uu ? inv1 : inv0;
    ctx[((size_t)b * U + u0 + uu) * D + hh * DH + dh] = tot * inv;
  }
}

// Fused base+crow (+map fold, R20/R21-verified): grid B*(U+1)+8.
__global__ __launch_bounds__(D) void k_bc2(const float* __restrict__ ctx,
                                           const float* __restrict__ wo,
                                           const float* __restrict__ wob,
                                           const int* __restrict__ idx,
                                           float* __restrict__ ctxo,
                                           float* __restrict__ baseo,
                                           int* __restrict__ map) {
  int i = blockIdx.x;
  if (i >= B * (U + 1)) {
    int t = (i - B * (U + 1)) * D + threadIdx.x;   // 8 blocks x 128 = 1024
    int m = -1;
    for (int u = 0; u < U; ++u)
      if (idx[u] == t) m = u;
    map[t] = m;
    return;
  }
  int b = i / (U + 1), u = i - b * (U + 1);
  int d = threadIdx.x;
  __shared__ float cs[D];
  if (u < U) {
    cs[d] = ctx[((size_t)b * U + u) * D + d];
  } else {
    float s = 0.f;
    for (int uu = 0; uu < U; ++uu) s += ctx[((size_t)b * U + uu) * D + d];
    cs[d] = s * (1.f / (float)U);
  }
  __syncthreads();
  float acc = wob[d];
  for (int k = 0; k < D; ++k) acc += cs[k] * wo[k * D + d];
  if (u < U) ctxo[((size_t)b * U + u) * D + d] = acc;
  else       baseo[(size_t)b * D + d] = acc;
}

// Fused LN1 + FF + residual + LN2 (v5b, R17/R21-verified best: 148-151 us).
// 32 rows/block, 512 threads.
constexpr int RF2 = 32;
constexpr int YSS = 129;   // ys row stride (f32)
__global__ __launch_bounds__(512) void k_ff5b(
    const float* __restrict__ h,              // pre-LN1 h
    const float* __restrict__ ctxo,
    const float* __restrict__ baseo,
    const int* __restrict__ map,
    const float* __restrict__ g1,
    const float* __restrict__ b1n,
    const unsigned short* __restrict__ w1t,   // [512][128] f16 (n-major)
    const float* __restrict__ b1,
    const unsigned short* __restrict__ w2t,   // [128][512] f16 (n-major)
    const float* __restrict__ b2,
    const float* __restrict__ g2,
    const float* __restrict__ bb2,
    float* __restrict__ hout) {
  __shared__ unsigned short hsb[RF2 * 128];  // swizzled f16 LN1 output
  __shared__ unsigned short g16[RF2][520];   // gelu out; overlaid by f32 ys[32][129]

  const int tid = threadIdx.x;
  const int r0 = blockIdx.x * RF2;

  // ---- stage: y = h + attn_out; LN1 (16-lane groups); -> swizzled f16 hsb ----
  {
    int m = tid >> 4, kc = tid & 15;
    int row = r0 + m;
    int b = row >> 10, t = row & (T - 1);
    int u = map[t];
    const float* src = (u >= 0) ? ctxo + ((size_t)b * U + u) * D
                                : baseo + (size_t)b * D;
    const float* hp = h + (size_t)row * D + kc * 8;
    float4 x0 = *(const float4*)hp;
    float4 x1 = *(const float4*)(hp + 4);
    float4 a0 = *(const float4*)(src + kc * 8);
    float4 a1 = *(const float4*)(src + kc * 8 + 4);
    float y0 = x0.x + a0.x, y1 = x0.y + a0.y, y2 = x0.z + a0.z, y3 = x0.w + a0.w;
    float y4 = x1.x + a1.x, y5 = x1.y + a1.y, y6 = x1.z + a1.z, y7 = x1.w + a1.w;
    float s = y0 + y1 + y2 + y3 + y4 + y5 + y6 + y7;
#pragma unroll
    for (int off = 8; off; off >>= 1) s += __shfl_xor(s, off, 16);
    float mu = s * (1.f / D);
    float e0 = y0 - mu, e1 = y1 - mu, e2 = y2 - mu, e3 = y3 - mu;
    float e4 = y4 - mu, e5 = y5 - mu, e6 = y6 - mu, e7 = y7 - mu;
    float v2 = e0 * e0 + e1 * e1 + e2 * e2 + e3 * e3 +
               e4 * e4 + e5 * e5 + e6 * e6 + e7 * e7;
#pragma unroll
    for (int off = 8; off; off >>= 1) v2 += __shfl_xor(v2, off, 16);
    float inv = rsqrtf(v2 * (1.f / D) + 1e-5f);
    float4 gv0 = *(const float4*)(g1 + kc * 8);
    float4 gv1 = *(const float4*)(g1 + kc * 8 + 4);
    float4 bv0 = *(const float4*)(b1n + kc * 8);
    float4 bv1 = *(const float4*)(b1n + kc * 8 + 4);
    f16x8 p;
    p[0] = (_Float16)(e0 * inv * gv0.x + bv0.x);
    p[1] = (_Float16)(e1 * inv * gv0.y + bv0.y);
    p[2] = (_Float16)(e2 * inv * gv0.z + bv0.z);
    p[3] = (_Float16)(e3 * inv * gv0.w + bv0.w);
    p[4] = (_Float16)(e4 * inv * gv1.x + bv1.x);
    p[5] = (_Float16)(e5 * inv * gv1.y + bv1.y);
    p[6] = (_Float16)(e6 * inv * gv1.z + bv1.z);
    p[7] = (_Float16)(e7 * inv * gv1.w + bv1.w);
    int byte = (m << 8) + (kc << 4);
    byte ^= (m & 7) << 4;
    *(f16x8*)((char*)hsb + byte) = p;
  }
  __syncthreads();

  const int wv = tid >> 6;
  const int l15 = tid & 15;
  const int lq = (tid & 63) >> 4;

  f16x8 afr[2][4];
#pragma unroll
  for (int mt = 0; mt < 2; ++mt)
#pragma unroll
    for (int ks = 0; ks < 4; ++ks) {
      int m = mt * 16 + l15;
      int byte = (m << 8) + ks * 64 + (lq << 4);
      byte ^= (m & 7) << 4;
      afr[mt][ks] = *(const f16x8*)((const char*)hsb + byte);
    }

  // ---- phase 1 (R14-verified): g16 = f16(gelu(h1 @ w1 + b1)) ----
  for (int nt = 0; nt < 4; ++nt) {
    int n0 = wv * 64 + nt * 16;
    const unsigned short* wp = w1t + (size_t)(n0 + l15) * 128 + lq * 8;
    f32x4 a0 = (f32x4){0.f, 0.f, 0.f, 0.f};
    f32x4 a1 = (f32x4){0.f, 0.f, 0.f, 0.f};
#pragma unroll
    for (int ks = 0; ks < 4; ++ks) {
      f16x8 bf = *(const f16x8*)(wp + ks * 32);
      a0 = __builtin_amdgcn_mfma_f32_16x16x32_f16(afr[0][ks], bf, a0, 0, 0, 0);
      a1 = __builtin_amdgcn_mfma_f32_16x16x32_f16(afr[1][ks], bf, a1, 0, 0, 0);
    }
    float bcol = b1[n0 + l15];
#pragma unroll
    for (int r = 0; r < 4; ++r) {
      int row0 = 4 * lq + r;
      float v0 = a0[r] + bcol;
      v0 = 0.5f * v0 * (1.f + erf_fast(v0 * 0.70710678118654752f));
      g16[row0][n0 + l15] = f2h(v0);
      float v1 = a1[r] + bcol;
      v1 = 0.5f * v1 * (1.f + erf_fast(v1 * 0.70710678118654752f));
      g16[row0 + 16][n0 + l15] = f2h(v1);
    }
  }
  __syncthreads();

  // ---- phase 2 (R13 ILP split, R14-verified): C2 = G @ w2 ----
  f32x4 a2a[2], a2b[2];
  a2a[0] = (f32x4){0.f, 0.f, 0.f, 0.f};
  a2a[1] = (f32x4){0.f, 0.f, 0.f, 0.f};
  a2b[0] = (f32x4){0.f, 0.f, 0.f, 0.f};
  a2b[1] = (f32x4){0.f, 0.f, 0.f, 0.f};
  const int ncol = wv * 16 + l15;
  const unsigned short* wp2b = w2t + (size_t)ncol * 512;
  for (int ks = 0; ks < 8; ++ks) {
    int k0 = ks * 32 + lq * 8;
    int k1 = (ks + 8) * 32 + lq * 8;
    f16x8 x0 = *(const f16x8*)&g16[l15][k0];
    f16x8 x1 = *(const f16x8*)&g16[16 + l15][k0];
    f16x8 w0 = *(const f16x8*)(wp2b + k0);
    a2a[0] = __builtin_amdgcn_mfma_f32_16x16x32_f16(x0, w0, a2a[0], 0, 0, 0);
    a2a[1] = __builtin_amdgcn_mfma_f32_16x16x32_f16(x1, w0, a2a[1], 0, 0, 0);
    f16x8 y0 = *(const f16x8*)&g16[l15][k1];
    f16x8 y1 = *(const f16x8*)&g16[16 + l15][k1];
    f16x8 w1 = *(const f16x8*)(wp2b + k1);
    a2b[0] = __builtin_amdgcn_mfma_f32_16x16x32_f16(y0, w1, a2b[0], 0, 0, 0);
    a2b[1] = __builtin_amdgcn_mfma_f32_16x16x32_f16(y1, w1, a2b[1], 0, 0, 0);
  }
  f32x4 acc2[2];
#pragma unroll
  for (int mt = 0; mt < 2; ++mt) {
    acc2[mt][0] = a2a[mt][0] + a2b[mt][0];
    acc2[mt][1] = a2a[mt][1] + a2b[mt][1];
    acc2[mt][2] = a2a[mt][2] + a2b[mt][2];
    acc2[mt][3] = a2a[mt][3] + a2b[mt][3];
  }
  __syncthreads();   // all g16 reads done -> overlay ys

  float* ys = (float*)&g16[0][0];            // [32][129] f32 overlay
  {
    float bc = b2[ncol];
#pragma unroll
    for (int mt = 0; mt < 2; ++mt)
#pragma unroll
      for (int r = 0; r < 4; ++r) {
        int row = mt * 16 + 4 * lq + r;
        int byte = (row << 8) + ((ncol * 2) ^ ((row & 7) << 4));
        float h1 = (float)(*(const _Float16*)((const char*)hsb + byte));
        ys[row * YSS + ncol] = h1 + acc2[mt][r] + bc;
      }
  }
  __syncthreads();

  // ---- LN2 + output: barrier-free, each 16-lane group owns one row (R17-verified) ----
  {
    int row = tid >> 4, lane16 = tid & 15;
    const float* yr = ys + row * YSS;
    float yv[8];
    float s = 0.f;
#pragma unroll
    for (int j = 0; j < 8; ++j) {
      yv[j] = yr[lane16 + j * 16];
      s += yv[j];
    }
#pragma unroll
    for (int off = 8; off; off >>= 1) s += __shfl_xor(s, off, 16);
    float mu = s * (1.f / D);
    float v2 = 0.f;
#pragma unroll
    for (int j = 0; j < 8; ++j) {
      float e = yv[j] - mu;
      v2 += e * e;
    }
#pragma unroll
    for (int off = 8; off; off >>= 1) v2 += __shfl_xor(v2, off, 16);
    float inv = rsqrtf(v2 * (1.f / D) + 1e-5f);
    float* op = hout + (size_t)(r0 + row) * D;
#pragma unroll
    for (int j = 0; j < 8; ++j) {
      int dd = lane16 + j * 16;
      op[dd] = (yv[j] - mu) * inv * g2[dd] + bb2[dd];
    }
  }
}

// out[b] = LN(h[b,T-1,:]) @ head_w + head_wb
__global__ __launch_bounds__(D) void k_head(const float* __restrict__ h,
                                            const float* __restrict__ g,
                                            const float* __restrict__ bb,
                                            const float* __restrict__ hw,
                                            const float* __restrict__ hwb,
                                            float* __restrict__ out) {
  int b = blockIdx.x, d = threadIdx.x;
  float y = h[((size_t)b * T + (T - 1)) * D + d];
  __shared__ float red[2];
  float s = y;
  for (int off = 32; off; off >>= 1) s += __shfl_down(s, off);
  if ((threadIdx.x & 63) == 0) red[threadIdx.x >> 6] = s;
  __syncthreads();
  float m = (red[0] + red[1]) * (1.f / D);
  __syncthreads();
  float e = y - m;
  float v = e * e;
  for (int off = 32; off; off >>= 1) v += __shfl_down(v, off);
  if ((threadIdx.x & 63) == 0) red[threadIdx.x >> 6] = v;
  __syncthreads();
  float inv = rsqrtf((red[0] + red[1]) * (1.f / D) + 1e-5f);
  __syncthreads();
  float last = e * inv * g[d] + bb[d];
  float p = last * hw[d];
  for (int off = 32; off; off >>= 1) p += __shfl_down(p, off);
  if ((threadIdx.x & 63) == 0) red[threadIdx.x >> 6] = p;
  __syncthreads();
  if (threadIdx.x == 0) out[b] = red[0] + red[1] + hwb[0];
}

// ---------------- launch ----------------

extern "C" void kernel_launch(void* const* d_in, const int* in_sizes, int n_in,
                              void* d_out, int out_size, void* d_ws, size_t ws_size,
                              hipStream_t stream) {
  const float* x       = (const float*)d_in[0];
  const int*   idx     = (const int*)d_in[1];
  const float* proj_w  = (const float*)d_in[2];
  const float* proj_b  = (const float*)d_in[3];
  const float* wq      = (const float*)d_in[4];
  const float* wk      = (const float*)d_in[5];
  const float* wv      = (const float*)d_in[6];
  const float* wo      = (const float*)d_in[7];
  const float* wo_b    = (const float*)d_in[8];
  const float* ln1_g   = (const float*)d_in[9];
  const float* ln1_b   = (const float*)d_in[10];
  const float* ff1_w   = (const float*)d_in[11];
  const float* ff1_b   = (const float*)d_in[12];
  const float* ff2_w   = (const float*)d_in[13];
  const float* ff2_b   = (const float*)d_in[14];
  const float* ln2_g   = (const float*)d_in[15];
  const float* ln2_b   = (const float*)d_in[16];
  const float* head_g  = (const float*)d_in[17];
  const float* head_bb = (const float*)d_in[18];
  const float* head_w  = (const float*)d_in[19];
  const float* head_wb = (const float*)d_in[20];
  float* out = (float*)d_out;

  float* wsf  = (float*)d_ws;
  float* h    = wsf;
  float* kreg = h    + (size_t)B * T * D;   // region reused for f16 K
  float* vreg = kreg + (size_t)B * T * D;   // region reused for f16 V
  float* qs   = vreg + (size_t)B * T * D;   // (unused now; layout kept)
  float* ctx  = qs   + (size_t)B * U * D;
  float* ctxo = ctx  + (size_t)B * U * D;
  float* baseo= ctxo + (size_t)B * U * D;
  int*   map  = (int*)(baseo + (size_t)B * D);
  unsigned short* kbuf16 = (unsigned short*)kreg;    // [B][H][T][DH] f16
  unsigned short* vbuf16 = (unsigned short*)vreg;
  // dedicated per-layer f16 weight region (beyond map)
  unsigned short* wbuf = (unsigned short*)(map + 1024);
  const size_t PL = 16384 + 16384 + 65536 + 65536;   // ushorts per layer

  for (int l = 0; l < L; ++l) {
    unsigned short* wkT = wbuf + (size_t)l * PL;
    unsigned short* wvT = wkT + 16384;
    unsigned short* w1T = wvT + 16384;
    unsigned short* w2T = w1T + 65536;
    k_prep_all<<<640, 256, 0, stream>>>(wk + (size_t)l * D * D,
                                        wv + (size_t)l * D * D,
                                        ff1_w + (size_t)l * D * FF,
                                        ff2_w + (size_t)l * FF * D,
                                        wkT, wvT, w1T, w2T);
  }

  k_proj<<<B * T, D, 0, stream>>>(x, proj_w, proj_b, h);

  for (int l = 0; l < L; ++l) {
    const float* wq_l = wq + (size_t)l * D * D;
    const float* wo_l = wo + (size_t)l * D * D;
    const int*   idx_l = idx + l * U;
    unsigned short* wkT = wbuf + (size_t)l * PL;
    unsigned short* wvT = wkT + 16384;
    unsigned short* w1T = wvT + 16384;
    unsigned short* w2T = w1T + 65536;

    k_kv_mfma2<<<B * T / 16, 256, 0, stream>>>(h, wkT, wvT, kbuf16, vbuf16);
    k_attn9<<<B * H * 17, 256, 0, stream>>>(h, idx_l, wq_l, kbuf16, vbuf16, ctx);
    k_bc2<<<B * (U + 1) + 8, D, 0, stream>>>(ctx, wo_l, wo_b + l * D, idx_l,
                                             ctxo, baseo, map);
    k_ff5b<<<B * T / RF2, 512, 0, stream>>>(h, ctxo, baseo, map,
                                            ln1_g + l * D, ln1_b + l * D,
                                            w1T, ff1_b + l * FF,
                                            w2T, ff2_b + l * D,
                                            ln2_g + l * D, ln2_b + l * D, h);
  }

  k_head<<<B, D, 0, stream>>>(h, head_g, head_bb, head_w, head_wb, out);
}

// Round 24
// 742.848 us; speedup vs baseline: 1.0124x; 1.0124x over previous
//
#include <hip/hip_runtime.h>
#include <math.h>

// Problem constants
constexpr int B  = 128;
constexpr int T  = 1024;
constexpr int IN_DIM = 32;
constexpr int D  = 128;
constexpr int H  = 8;
constexpr int DH = 16;   // D/H
constexpr int L  = 2;
constexpr int U  = 34;   // int(5*ln(1025))
constexpr int FF = 512;  // 4*D

typedef __attribute__((ext_vector_type(8))) _Float16 f16x8;
typedef __attribute__((ext_vector_type(2))) _Float16 h2;
typedef __attribute__((ext_vector_type(4))) float f32x4;

__device__ __forceinline__ unsigned short f2h(float x) {
  union { _Float16 h; unsigned short u; } v;
  v.h = (_Float16)x;
  return v.u;
}

__device__ __forceinline__ h2 shfl_xor_h2(h2 v, int off) {
  union { h2 h; int i; } u;
  u.h = v;
  u.i = __shfl_xor(u.i, off);
  return u.h;
}

// Branch-free erf, Abramowitz-Stegun 7.1.26 (|err| <= 1.5e-7)  (R10-verified)
__device__ __forceinline__ float erf_fast(float x) {
  float a = fabsf(x);
  float t = __builtin_amdgcn_rcpf(fmaf(0.3275911f, a, 1.f));
  float y = t * (0.254829592f +
            t * (-0.284496736f +
            t * (1.421413741f +
            t * (-1.453152027f +
            t * 1.061405429f))));
  float r = 1.f - y * __expf(-a * a);
  return copysignf(r, x);
}

// ---------------- helpers ----------------

// Paired block reductions (one barrier pair for two values)  (R15-verified)
__device__ __forceinline__ void blockMax2(float& a, float& b, float* red) {
  for (int off = 32; off; off >>= 1) {
    a = fmaxf(a, __shfl_down(a, off));
    b = fmaxf(b, __shfl_down(b, off));
  }
  if ((threadIdx.x & 63) == 0) {
    red[threadIdx.x >> 6] = a;
    red[4 + (threadIdx.x >> 6)] = b;
  }
  __syncthreads();
  a = fmaxf(fmaxf(red[0], red[1]), fmaxf(red[2], red[3]));
  b = fmaxf(fmaxf(red[4], red[5]), fmaxf(red[6], red[7]));
  __syncthreads();
}

__device__ __forceinline__ void blockSum2(float& a, float& b, float* red) {
  for (int off = 32; off; off >>= 1) {
    a += __shfl_down(a, off);
    b += __shfl_down(b, off);
  }
  if ((threadIdx.x & 63) == 0) {
    red[threadIdx.x >> 6] = a;
    red[4 + (threadIdx.x >> 6)] = b;
  }
  __syncthreads();
  a = red[0] + red[1] + red[2] + red[3];
  b = red[4] + red[5] + red[6] + red[7];
  __syncthreads();
}

// ---------------- kernels ----------------

// All-weights transpose+f16 for one layer. 163840 elements -> 640 blocks x 256.
__global__ void k_prep_all(const float* __restrict__ wk_l,
                           const float* __restrict__ wv_l,
                           const float* __restrict__ w1_l,   // [128][512]
                           const float* __restrict__ w2_l,   // [512][128]
                           unsigned short* __restrict__ wkT,
                           unsigned short* __restrict__ wvT,
                           unsigned short* __restrict__ w1T,
                           unsigned short* __restrict__ w2T) {
  int idx = blockIdx.x * 256 + threadIdx.x;
  if (idx < 16384) {
    int n = idx >> 7, k = idx & 127;
    wkT[idx] = f2h(wk_l[k * 128 + n]);
  } else if (idx < 32768) {
    int j = idx - 16384;
    int n = j >> 7, k = j & 127;
    wvT[j] = f2h(wv_l[k * 128 + n]);
  } else if (idx < 98304) {
    int j = idx - 32768;                 // out[n*128+k], n<512, k<128
    int n = j >> 7, k = j & 127;
    w1T[j] = f2h(w1_l[k * 512 + n]);
  } else if (idx < 163840) {
    int j = idx - 98304;                 // out[n*512+k], n<128, k<512
    int n = j >> 9, k = j & 511;
    w2T[j] = f2h(w2_l[k * 128 + n]);
  }
}

// h[b,t,:] = x[b,t,:] @ proj_w + proj_b + pos_enc(t,:)
__global__ __launch_bounds__(D) void k_proj(const float* __restrict__ x,
                                            const float* __restrict__ pw,
                                            const float* __restrict__ pb,
                                            float* __restrict__ h) {
  int row = blockIdx.x;            // b*T + t
  int t = row & (T - 1);
  int d = threadIdx.x;
  __shared__ float xs[IN_DIM];
  if (threadIdx.x < IN_DIM) xs[threadIdx.x] = x[(size_t)row * IN_DIM + threadIdx.x];
  __syncthreads();
  float acc = pb[d];
#pragma unroll
  for (int i = 0; i < IN_DIM; ++i) acc += xs[i] * pw[i * D + d];
  int j = d >> 1;
  float div = __expf((float)(2 * j) * (-logf(10000.f) / (float)D));
  float ang = (float)t * div;
  acc += (d & 1) ? __cosf(ang) : __sinf(ang);
  h[(size_t)row * D + d] = acc;
}

// Fused K,V projection via MFMA -> head-major f16 [B][H][T][DH]. (R8-verified)
__global__ __launch_bounds__(256) void k_kv_mfma2(
    const float* __restrict__ h,
    const unsigned short* __restrict__ wkt,   // [128][128] f16 (n-major)
    const unsigned short* __restrict__ wvt,
    unsigned short* __restrict__ kbuf, unsigned short* __restrict__ vbuf) {
  __shared__ unsigned short hsb[16 * 128];    // XOR-swizzled f16 (R5-verified)
  const int tid = threadIdx.x;
  const int r0 = blockIdx.x * 16;
  {
    int m = tid >> 4, kc = tid & 15;
    const float* src = h + (size_t)(r0 + m) * D + kc * 8;
    float4 x0 = *(const float4*)src;
    float4 x1 = *(const float4*)(src + 4);
    f16x8 p;
    p[0] = (_Float16)x0.x; p[1] = (_Float16)x0.y;
    p[2] = (_Float16)x0.z; p[3] = (_Float16)x0.w;
    p[4] = (_Float16)x1.x; p[5] = (_Float16)x1.y;
    p[6] = (_Float16)x1.z; p[7] = (_Float16)x1.w;
    int byte = (m << 8) + (kc << 4);
    byte ^= (m & 7) << 4;
    *(f16x8*)((char*)hsb + byte) = p;
  }
  __syncthreads();
  const int wv = tid >> 6;
  const int l15 = tid & 15;
  const int lq = (tid & 63) >> 4;
  f16x8 afr[4];
#pragma unroll
  for (int ks = 0; ks < 4; ++ks) {
    int byte = (l15 << 8) + ks * 64 + (lq << 4);
    byte ^= (l15 & 7) << 4;
    afr[ks] = *(const f16x8*)((const char*)hsb + byte);
  }
  const unsigned short* wt = (wv < 2) ? wkt : wvt;
  unsigned short* outp = (wv < 2) ? kbuf : vbuf;
  const int cw = (wv & 1) * 64;
  f32x4 acc[4];
#pragma unroll
  for (int nt = 0; nt < 4; ++nt) acc[nt] = (f32x4){0.f, 0.f, 0.f, 0.f};
#pragma unroll
  for (int nt = 0; nt < 4; ++nt) {
    const unsigned short* wp = wt + (size_t)(cw + nt * 16 + l15) * 128 + lq * 8;
#pragma unroll
    for (int ks = 0; ks < 4; ++ks) {
      f16x8 bf = *(const f16x8*)(wp + ks * 32);
      acc[nt] = __builtin_amdgcn_mfma_f32_16x16x32_f16(afr[ks], bf, acc[nt], 0, 0, 0);
    }
  }
#pragma unroll
  for (int nt = 0; nt < 4; ++nt) {
    int col = cw + nt * 16 + l15;
    int hcol = col >> 4, dh = col & 15;
#pragma unroll
    for (int r = 0; r < 4; ++r) {
      int row = r0 + 4 * lq + r;             // C/D: row = 4*(lane>>4)+reg
      int b = row >> 10, t = row & (T - 1);
      outp[(((size_t)b * H + hcol) * T + t) * DH + dh] = f2h(acc[nt][r]);
    }
  }
}

// qs[b,u,:] = h[b, idx[u], :] @ wq
__global__ __launch_bounds__(D) void k_qrow(const float* __restrict__ h,
                                            const int* __restrict__ idx,
                                            const float* __restrict__ wq,
                                            float* __restrict__ qs) {
  int bu = blockIdx.x;             // b*U + u
  int b = bu / U, u = bu - b * U;
  int t = idx[u];
  __shared__ float hs[D];
  hs[threadIdx.x] = h[((size_t)b * T + t) * D + threadIdx.x];
  __syncthreads();
  int d = threadIdx.x;
  float acc = 0.f;
  for (int k = 0; k < D; ++k) acc += hs[k] * wq[k * D + d];
  qs[(size_t)bu * D + d] = acc;
}

// Attention v8 (R22-verified best): scores in registers, dot2 QK + pk_fma PV.
// grid = B*H*17, block = 256.
__global__ __launch_bounds__(256) void k_attn8(const float* __restrict__ qs,
                                               const unsigned short* __restrict__ kbuf,
                                               const unsigned short* __restrict__ vbuf,
                                               float* __restrict__ ctx) {
  constexpr int NWG = B * H * 17;
  int bid = blockIdx.x;
  int orig = (bid & 7) * (NWG / 8) + (bid >> 3);   // bijective XCD chunk (R9-verified)
  int up = orig % 17;
  int gb = orig / 17;
  int hh = gb & 7, b = gb >> 3;
  int u0 = up * 2;

  __shared__ h2 qh[2][8];
  __shared__ float red[8];
  __shared__ float redw[4][2][DH];
  const int tid = threadIdx.x;

  if (tid < 16) {
    int uu = tid >> 3, jj = tid & 7;
    const float* qp = qs + ((size_t)b * U + u0 + uu) * D + hh * DH + jj * 2;
    qh[uu][jj] = (h2){(_Float16)qp[0], (_Float16)qp[1]};
  }
  __syncthreads();
  const unsigned short* kg = kbuf + (size_t)gb * T * DH;
  const unsigned short* vg = vbuf + (size_t)gb * T * DH;

  h2 q0[8], q1[8];
#pragma unroll
  for (int j = 0; j < 8; ++j) { q0[j] = qh[0][j]; q1[j] = qh[1][j]; }

  // QK: scores stay in registers (4 t-steps per thread per u)
  float sc0[4], sc1[4];
  float lmax0 = -1e30f, lmax1 = -1e30f;
#pragma unroll
  for (int p = 0; p < 4; ++p) {
    int t = p * 256 + tid;
    const h2* k2 = (const h2*)(kg + t * DH);
    float s0 = 0.f, s1 = 0.f;
#pragma unroll
    for (int j = 0; j < 8; ++j) {
      h2 kv = k2[j];
      s0 = __builtin_amdgcn_fdot2(q0[j], kv, s0, false);
      s1 = __builtin_amdgcn_fdot2(q1[j], kv, s1, false);
    }
    s0 *= 0.25f; s1 *= 0.25f;        // 1/sqrt(16)
    sc0[p] = s0; sc1[p] = s1;
    lmax0 = fmaxf(lmax0, s0);
    lmax1 = fmaxf(lmax1, s1);
  }
  blockMax2(lmax0, lmax1, red);
  float lsum0 = 0.f, lsum1 = 0.f;
#pragma unroll
  for (int p = 0; p < 4; ++p) {
    sc0[p] = __expf(sc0[p] - lmax0);
    sc1[p] = __expf(sc1[p] - lmax1);
    lsum0 += sc0[p];
    lsum1 += sc1[p];
  }
  blockSum2(lsum0, lsum1, red);
  float inv0 = 1.f / lsum0;
  float inv1 = 1.f / lsum1;

  h2 p0[8], p1[8];
#pragma unroll
  for (int j = 0; j < 8; ++j) { p0[j] = (h2){0, 0}; p1[j] = (h2){0, 0}; }
#pragma unroll
  for (int p = 0; p < 4; ++p) {
    int t = p * 256 + tid;
    const h2* v2 = (const h2*)(vg + t * DH);
    _Float16 a0 = (_Float16)sc0[p], a1 = (_Float16)sc1[p];
    h2 a0h = (h2){a0, a0}, a1h = (h2){a1, a1};
#pragma unroll
    for (int j = 0; j < 8; ++j) {
      h2 vv = v2[j];
      p0[j] += a0h * vv;
      p1[j] += a1h * vv;
    }
  }
#pragma unroll
  for (int j = 0; j < 8; ++j) {
#pragma unroll
    for (int off = 32; off; off >>= 1) {
      p0[j] += shfl_xor_h2(p0[j], off);
      p1[j] += shfl_xor_h2(p1[j], off);
    }
  }
  const int wv = tid >> 6, lane = tid & 63;
  if (lane == 0) {
#pragma unroll
    for (int j = 0; j < 8; ++j) {
      redw[wv][0][2 * j]     = (float)p0[j][0];
      redw[wv][0][2 * j + 1] = (float)p0[j][1];
      redw[wv][1][2 * j]     = (float)p1[j][0];
      redw[wv][1][2 * j + 1] = (float)p1[j][1];
    }
  }
  __syncthreads();
  if (tid < 32) {
    int uu = tid >> 4, dh = tid & 15;
    float tot = redw[0][uu][dh] + redw[1][uu][dh] + redw[2][uu][dh] + redw[3][uu][dh];
    float inv = uu ? inv1 : inv0;
    ctx[((size_t)b * U + u0 + uu) * D + hh * DH + dh] = tot * inv;
  }
}

// Fused base+crow (+map fold, R20/R21-verified): grid B*(U+1)+8.
__global__ __launch_bounds__(D) void k_bc2(const float* __restrict__ ctx,
                                           const float* __restrict__ wo,
                                           const float* __restrict__ wob,
                                           const int* __restrict__ idx,
                                           float* __restrict__ ctxo,
                                           float* __restrict__ baseo,
                                           int* __restrict__ map) {
  int i = blockIdx.x;
  if (i >= B * (U + 1)) {
    int t = (i - B * (U + 1)) * D + threadIdx.x;   // 8 blocks x 128 = 1024
    int m = -1;
    for (int u = 0; u < U; ++u)
      if (idx[u] == t) m = u;
    map[t] = m;
    return;
  }
  int b = i / (U + 1), u = i - b * (U + 1);
  int d = threadIdx.x;
  __shared__ float cs[D];
  if (u < U) {
    cs[d] = ctx[((size_t)b * U + u) * D + d];
  } else {
    float s = 0.f;
    for (int uu = 0; uu < U; ++uu) s += ctx[((size_t)b * U + uu) * D + d];
    cs[d] = s * (1.f / (float)U);
  }
  __syncthreads();
  float acc = wob[d];
  for (int k = 0; k < D; ++k) acc += cs[k] * wo[k * D + d];
  if (u < U) ctxo[((size_t)b * U + u) * D + d] = acc;
  else       baseo[(size_t)b * D + d] = acc;
}

// Fused LN1 + FF + residual + LN2 (v5b, R17/R21-verified best: 148-151 us).
// 32 rows/block, 512 threads.
constexpr int RF2 = 32;
constexpr int YSS = 129;   // ys row stride (f32)
__global__ __launch_bounds__(512) void k_ff5b(
    const float* __restrict__ h,              // pre-LN1 h
    const float* __restrict__ ctxo,
    const float* __restrict__ baseo,
    const int* __restrict__ map,
    const float* __restrict__ g1,
    const float* __restrict__ b1n,
    const unsigned short* __restrict__ w1t,   // [512][128] f16 (n-major)
    const float* __restrict__ b1,
    const unsigned short* __restrict__ w2t,   // [128][512] f16 (n-major)
    const float* __restrict__ b2,
    const float* __restrict__ g2,
    const float* __restrict__ bb2,
    float* __restrict__ hout) {
  __shared__ unsigned short hsb[RF2 * 128];  // swizzled f16 LN1 output
  __shared__ unsigned short g16[RF2][520];   // gelu out; overlaid by f32 ys[32][129]

  const int tid = threadIdx.x;
  const int r0 = blockIdx.x * RF2;

  // ---- stage: y = h + attn_out; LN1 (16-lane groups); -> swizzled f16 hsb ----
  {
    int m = tid >> 4, kc = tid & 15;
    int row = r0 + m;
    int b = row >> 10, t = row & (T - 1);
    int u = map[t];
    const float* src = (u >= 0) ? ctxo + ((size_t)b * U + u) * D
                                : baseo + (size_t)b * D;
    const float* hp = h + (size_t)row * D + kc * 8;
    float4 x0 = *(const float4*)hp;
    float4 x1 = *(const float4*)(hp + 4);
    float4 a0 = *(const float4*)(src + kc * 8);
    float4 a1 = *(const float4*)(src + kc * 8 + 4);
    float y0 = x0.x + a0.x, y1 = x0.y + a0.y, y2 = x0.z + a0.z, y3 = x0.w + a0.w;
    float y4 = x1.x + a1.x, y5 = x1.y + a1.y, y6 = x1.z + a1.z, y7 = x1.w + a1.w;
    float s = y0 + y1 + y2 + y3 + y4 + y5 + y6 + y7;
#pragma unroll
    for (int off = 8; off; off >>= 1) s += __shfl_xor(s, off, 16);
    float mu = s * (1.f / D);
    float e0 = y0 - mu, e1 = y1 - mu, e2 = y2 - mu, e3 = y3 - mu;
    float e4 = y4 - mu, e5 = y5 - mu, e6 = y6 - mu, e7 = y7 - mu;
    float v2 = e0 * e0 + e1 * e1 + e2 * e2 + e3 * e3 +
               e4 * e4 + e5 * e5 + e6 * e6 + e7 * e7;
#pragma unroll
    for (int off = 8; off; off >>= 1) v2 += __shfl_xor(v2, off, 16);
    float inv = rsqrtf(v2 * (1.f / D) + 1e-5f);
    float4 gv0 = *(const float4*)(g1 + kc * 8);
    float4 gv1 = *(const float4*)(g1 + kc * 8 + 4);
    float4 bv0 = *(const float4*)(b1n + kc * 8);
    float4 bv1 = *(const float4*)(b1n + kc * 8 + 4);
    f16x8 p;
    p[0] = (_Float16)(e0 * inv * gv0.x + bv0.x);
    p[1] = (_Float16)(e1 * inv * gv0.y + bv0.y);
    p[2] = (_Float16)(e2 * inv * gv0.z + bv0.z);
    p[3] = (_Float16)(e3 * inv * gv0.w + bv0.w);
    p[4] = (_Float16)(e4 * inv * gv1.x + bv1.x);
    p[5] = (_Float16)(e5 * inv * gv1.y + bv1.y);
    p[6] = (_Float16)(e6 * inv * gv1.z + bv1.z);
    p[7] = (_Float16)(e7 * inv * gv1.w + bv1.w);
    int byte = (m << 8) + (kc << 4);
    byte ^= (m & 7) << 4;
    *(f16x8*)((char*)hsb + byte) = p;
  }
  __syncthreads();

  const int wv = tid >> 6;
  const int l15 = tid & 15;
  const int lq = (tid & 63) >> 4;

  f16x8 afr[2][4];
#pragma unroll
  for (int mt = 0; mt < 2; ++mt)
#pragma unroll
    for (int ks = 0; ks < 4; ++ks) {
      int m = mt * 16 + l15;
      int byte = (m << 8) + ks * 64 + (lq << 4);
      byte ^= (m & 7) << 4;
      afr[mt][ks] = *(const f16x8*)((const char*)hsb + byte);
    }

  // ---- phase 1 (R14-verified): g16 = f16(gelu(h1 @ w1 + b1)) ----
  for (int nt = 0; nt < 4; ++nt) {
    int n0 = wv * 64 + nt * 16;
    const unsigned short* wp = w1t + (size_t)(n0 + l15) * 128 + lq * 8;
    f32x4 a0 = (f32x4){0.f, 0.f, 0.f, 0.f};
    f32x4 a1 = (f32x4){0.f, 0.f, 0.f, 0.f};
#pragma unroll
    for (int ks = 0; ks < 4; ++ks) {
      f16x8 bf = *(const f16x8*)(wp + ks * 32);
      a0 = __builtin_amdgcn_mfma_f32_16x16x32_f16(afr[0][ks], bf, a0, 0, 0, 0);
      a1 = __builtin_amdgcn_mfma_f32_16x16x32_f16(afr[1][ks], bf, a1, 0, 0, 0);
    }
    float bcol = b1[n0 + l15];
#pragma unroll
    for (int r = 0; r < 4; ++r) {
      int row0 = 4 * lq + r;
      float v0 = a0[r] + bcol;
      v0 = 0.5f * v0 * (1.f + erf_fast(v0 * 0.70710678118654752f));
      g16[row0][n0 + l15] = f2h(v0);
      float v1 = a1[r] + bcol;
      v1 = 0.5f * v1 * (1.f + erf_fast(v1 * 0.70710678118654752f));
      g16[row0 + 16][n0 + l15] = f2h(v1);
    }
  }
  __syncthreads();

  // ---- phase 2 (R13 ILP split, R14-verified): C2 = G @ w2 ----
  f32x4 a2a[2], a2b[2];
  a2a[0] = (f32x4){0.f, 0.f, 0.f, 0.f};
  a2a[1] = (f32x4){0.f, 0.f, 0.f, 0.f};
  a2b[0] = (f32x4){0.f, 0.f, 0.f, 0.f};
  a2b[1] = (f32x4){0.f, 0.f, 0.f, 0.f};
  const int ncol = wv * 16 + l15;
  const unsigned short* wp2b = w2t + (size_t)ncol * 512;
  for (int ks = 0; ks < 8; ++ks) {
    int k0 = ks * 32 + lq * 8;
    int k1 = (ks + 8) * 32 + lq * 8;
    f16x8 x0 = *(const f16x8*)&g16[l15][k0];
    f16x8 x1 = *(const f16x8*)&g16[16 + l15][k0];
    f16x8 w0 = *(const f16x8*)(wp2b + k0);
    a2a[0] = __builtin_amdgcn_mfma_f32_16x16x32_f16(x0, w0, a2a[0], 0, 0, 0);
    a2a[1] = __builtin_amdgcn_mfma_f32_16x16x32_f16(x1, w0, a2a[1], 0, 0, 0);
    f16x8 y0 = *(const f16x8*)&g16[l15][k1];
    f16x8 y1 = *(const f16x8*)&g16[16 + l15][k1];
    f16x8 w1 = *(const f16x8*)(wp2b + k1);
    a2b[0] = __builtin_amdgcn_mfma_f32_16x16x32_f16(y0, w1, a2b[0], 0, 0, 0);
    a2b[1] = __builtin_amdgcn_mfma_f32_16x16x32_f16(y1, w1, a2b[1], 0, 0, 0);
  }
  f32x4 acc2[2];
#pragma unroll
  for (int mt = 0; mt < 2; ++mt) {
    acc2[mt][0] = a2a[mt][0] + a2b[mt][0];
    acc2[mt][1] = a2a[mt][1] + a2b[mt][1];
    acc2[mt][2] = a2a[mt][2] + a2b[mt][2];
    acc2[mt][3] = a2a[mt][3] + a2b[mt][3];
  }
  __syncthreads();   // all g16 reads done -> overlay ys

  float* ys = (float*)&g16[0][0];            // [32][129] f32 overlay
  {
    float bc = b2[ncol];
#pragma unroll
    for (int mt = 0; mt < 2; ++mt)
#pragma unroll
      for (int r = 0; r < 4; ++r) {
        int row = mt * 16 + 4 * lq + r;
        int byte = (row << 8) + ((ncol * 2) ^ ((row & 7) << 4));
        float h1 = (float)(*(const _Float16*)((const char*)hsb + byte));
        ys[row * YSS + ncol] = h1 + acc2[mt][r] + bc;
      }
  }
  __syncthreads();

  // ---- LN2 + output: barrier-free, each 16-lane group owns one row (R17-verified) ----
  {
    int row = tid >> 4, lane16 = tid & 15;
    const float* yr = ys + row * YSS;
    float yv[8];
    float s = 0.f;
#pragma unroll
    for (int j = 0; j < 8; ++j) {
      yv[j] = yr[lane16 + j * 16];
      s += yv[j];
    }
#pragma unroll
    for (int off = 8; off; off >>= 1) s += __shfl_xor(s, off, 16);
    float mu = s * (1.f / D);
    float v2 = 0.f;
#pragma unroll
    for (int j = 0; j < 8; ++j) {
      float e = yv[j] - mu;
      v2 += e * e;
    }
#pragma unroll
    for (int off = 8; off; off >>= 1) v2 += __shfl_xor(v2, off, 16);
    float inv = rsqrtf(v2 * (1.f / D) + 1e-5f);
    float* op = hout + (size_t)(r0 + row) * D;
#pragma unroll
    for (int j = 0; j < 8; ++j) {
      int dd = lane16 + j * 16;
      op[dd] = (yv[j] - mu) * inv * g2[dd] + bb2[dd];
    }
  }
}

// out[b] = LN(h[b,T-1,:]) @ head_w + head_wb
__global__ __launch_bounds__(D) void k_head(const float* __restrict__ h,
                                            const float* __restrict__ g,
                                            const float* __restrict__ bb,
                                            const float* __restrict__ hw,
                                            const float* __restrict__ hwb,
                                            float* __restrict__ out) {
  int b = blockIdx.x, d = threadIdx.x;
  float y = h[((size_t)b * T + (T - 1)) * D + d];
  __shared__ float red[2];
  float s = y;
  for (int off = 32; off; off >>= 1) s += __shfl_down(s, off);
  if ((threadIdx.x & 63) == 0) red[threadIdx.x >> 6] = s;
  __syncthreads();
  float m = (red[0] + red[1]) * (1.f / D);
  __syncthreads();
  float e = y - m;
  float v = e * e;
  for (int off = 32; off; off >>= 1) v += __shfl_down(v, off);
  if ((threadIdx.x & 63) == 0) red[threadIdx.x >> 6] = v;
  __syncthreads();
  float inv = rsqrtf((red[0] + red[1]) * (1.f / D) + 1e-5f);
  __syncthreads();
  float last = e * inv * g[d] + bb[d];
  float p = last * hw[d];
  for (int off = 32; off; off >>= 1) p += __shfl_down(p, off);
  if ((threadIdx.x & 63) == 0) red[threadIdx.x >> 6] = p;
  __syncthreads();
  if (threadIdx.x == 0) out[b] = red[0] + red[1] + hwb[0];
}

// ---------------- launch ----------------

extern "C" void kernel_launch(void* const* d_in, const int* in_sizes, int n_in,
                              void* d_out, int out_size, void* d_ws, size_t ws_size,
                              hipStream_t stream) {
  const float* x       = (const float*)d_in[0];
  const int*   idx     = (const int*)d_in[1];
  const float* proj_w  = (const float*)d_in[2];
  const float* proj_b  = (const float*)d_in[3];
  const float* wq      = (const float*)d_in[4];
  const float* wk      = (const float*)d_in[5];
  const float* wv      = (const float*)d_in[6];
  const float* wo      = (const float*)d_in[7];
  const float* wo_b    = (const float*)d_in[8];
  const float* ln1_g   = (const float*)d_in[9];
  const float* ln1_b   = (const float*)d_in[10];
  const float* ff1_w   = (const float*)d_in[11];
  const float* ff1_b   = (const float*)d_in[12];
  const float* ff2_w   = (const float*)d_in[13];
  const float* ff2_b   = (const float*)d_in[14];
  const float* ln2_g   = (const float*)d_in[15];
  const float* ln2_b   = (const float*)d_in[16];
  const float* head_g  = (const float*)d_in[17];
  const float* head_bb = (const float*)d_in[18];
  const float* head_w  = (const float*)d_in[19];
  const float* head_wb = (const float*)d_in[20];
  float* out = (float*)d_out;

  float* wsf  = (float*)d_ws;
  float* h    = wsf;
  float* kreg = h    + (size_t)B * T * D;   // region reused for f16 K
  float* vreg = kreg + (size_t)B * T * D;   // region reused for f16 V
  float* qs   = vreg + (size_t)B * T * D;
  float* ctx  = qs   + (size_t)B * U * D;
  float* ctxo = ctx  + (size_t)B * U * D;
  float* baseo= ctxo + (size_t)B * U * D;
  int*   map  = (int*)(baseo + (size_t)B * D);
  unsigned short* kbuf16 = (unsigned short*)kreg;    // [B][H][T][DH] f16
  unsigned short* vbuf16 = (unsigned short*)vreg;
  // dedicated per-layer f16 weight region (beyond map)
  unsigned short* wbuf = (unsigned short*)(map + 1024);
  const size_t PL = 16384 + 16384 + 65536 + 65536;   // ushorts per layer

  for (int l = 0; l < L; ++l) {
    unsigned short* wkT = wbuf + (size_t)l * PL;
    unsigned short* wvT = wkT + 16384;
    unsigned short* w1T = wvT + 16384;
    unsigned short* w2T = w1T + 65536;
    k_prep_all<<<640, 256, 0, stream>>>(wk + (size_t)l * D * D,
                                        wv + (size_t)l * D * D,
                                        ff1_w + (size_t)l * D * FF,
                                        ff2_w + (size_t)l * FF * D,
                                        wkT, wvT, w1T, w2T);
  }

  k_proj<<<B * T, D, 0, stream>>>(x, proj_w, proj_b, h);

  for (int l = 0; l < L; ++l) {
    const float* wq_l = wq + (size_t)l * D * D;
    const float* wo_l = wo + (size_t)l * D * D;
    const int*   idx_l = idx + l * U;
    unsigned short* wkT = wbuf + (size_t)l * PL;
    unsigned short* wvT = wkT + 16384;
    unsigned short* w1T = wvT + 16384;
    unsigned short* w2T = w1T + 65536;

    k_kv_mfma2<<<B * T / 16, 256, 0, stream>>>(h, wkT, wvT, kbuf16, vbuf16);
    k_qrow<<<B * U, D, 0, stream>>>(h, idx_l, wq_l, qs);
    k_attn8<<<B * H * 17, 256, 0, stream>>>(qs, kbuf16, vbuf16, ctx);
    k_bc2<<<B * (U + 1) + 8, D, 0, stream>>>(ctx, wo_l, wo_b + l * D, idx_l,
                                             ctxo, baseo, map);
    k_ff5b<<<B * T / RF2, 512, 0, stream>>>(h, ctxo, baseo, map,
                                            ln1_g + l * D, ln1_b + l * D,
                                            w1T, ff1_b + l * FF,
                                            w2T, ff2_b + l * D,
                                            ln2_g + l * D, ln2_b + l * D, h);
  }

  k_head<<<B, D, 0, stream>>>(h, head_g, head_bb, head_w, head_wb, out);
}

// Round 25
// 737.592 us; speedup vs baseline: 1.0196x; 1.0071x over previous
//
#include <hip/hip_runtime.h>
#include <math.h>

// Problem constants
constexpr int B  = 128;
constexpr int T  = 1024;
constexpr int IN_DIM = 32;
constexpr int D  = 128;
constexpr int H  = 8;
constexpr int DH = 16;   // D/H
constexpr int L  = 2;
constexpr int U  = 34;   // int(5*ln(1025))
constexpr int FF = 512;  // 4*D

typedef __attribute__((ext_vector_type(8))) _Float16 f16x8;
typedef __attribute__((ext_vector_type(2))) _Float16 h2;
typedef __attribute__((ext_vector_type(4))) float f32x4;

__device__ __forceinline__ unsigned short f2h(float x) {
  union { _Float16 h; unsigned short u; } v;
  v.h = (_Float16)x;
  return v.u;
}

__device__ __forceinline__ h2 shfl_xor_h2(h2 v, int off) {
  union { h2 h; int i; } u;
  u.h = v;
  u.i = __shfl_xor(u.i, off);
  return u.h;
}

// Branch-free erf, Abramowitz-Stegun 7.1.26 (|err| <= 1.5e-7)  (R10-verified)
__device__ __forceinline__ float erf_fast(float x) {
  float a = fabsf(x);
  float t = __builtin_amdgcn_rcpf(fmaf(0.3275911f, a, 1.f));
  float y = t * (0.254829592f +
            t * (-0.284496736f +
            t * (1.421413741f +
            t * (-1.453152027f +
            t * 1.061405429f))));
  float r = 1.f - y * __expf(-a * a);
  return copysignf(r, x);
}

// ---------------- helpers ----------------

// Paired block reductions (one barrier pair for two values)  (R15-verified)
__device__ __forceinline__ void blockMax2(float& a, float& b, float* red) {
  for (int off = 32; off; off >>= 1) {
    a = fmaxf(a, __shfl_down(a, off));
    b = fmaxf(b, __shfl_down(b, off));
  }
  if ((threadIdx.x & 63) == 0) {
    red[threadIdx.x >> 6] = a;
    red[4 + (threadIdx.x >> 6)] = b;
  }
  __syncthreads();
  a = fmaxf(fmaxf(red[0], red[1]), fmaxf(red[2], red[3]));
  b = fmaxf(fmaxf(red[4], red[5]), fmaxf(red[6], red[7]));
  __syncthreads();
}

__device__ __forceinline__ void blockSum2(float& a, float& b, float* red) {
  for (int off = 32; off; off >>= 1) {
    a += __shfl_down(a, off);
    b += __shfl_down(b, off);
  }
  if ((threadIdx.x & 63) == 0) {
    red[threadIdx.x >> 6] = a;
    red[4 + (threadIdx.x >> 6)] = b;
  }
  __syncthreads();
  a = red[0] + red[1] + red[2] + red[3];
  b = red[4] + red[5] + red[6] + red[7];
  __syncthreads();
}

// ---------------- kernels ----------------

// All-weights transpose+f16 for one layer. 163840 elements -> 640 blocks x 256.
__global__ void k_prep_all(const float* __restrict__ wk_l,
                           const float* __restrict__ wv_l,
                           const float* __restrict__ w1_l,   // [128][512]
                           const float* __restrict__ w2_l,   // [512][128]
                           unsigned short* __restrict__ wkT,
                           unsigned short* __restrict__ wvT,
                           unsigned short* __restrict__ w1T,
                           unsigned short* __restrict__ w2T) {
  int idx = blockIdx.x * 256 + threadIdx.x;
  if (idx < 16384) {
    int n = idx >> 7, k = idx & 127;
    wkT[idx] = f2h(wk_l[k * 128 + n]);
  } else if (idx < 32768) {
    int j = idx - 16384;
    int n = j >> 7, k = j & 127;
    wvT[j] = f2h(wv_l[k * 128 + n]);
  } else if (idx < 98304) {
    int j = idx - 32768;                 // out[n*128+k], n<512, k<128
    int n = j >> 7, k = j & 127;
    w1T[j] = f2h(w1_l[k * 512 + n]);
  } else if (idx < 163840) {
    int j = idx - 98304;                 // out[n*512+k], n<128, k<512
    int n = j >> 9, k = j & 511;
    w2T[j] = f2h(w2_l[k * 128 + n]);
  }
}

// h[b,t,:] = x[b,t,:] @ proj_w + proj_b + pos_enc(t,:)
__global__ __launch_bounds__(D) void k_proj(const float* __restrict__ x,
                                            const float* __restrict__ pw,
                                            const float* __restrict__ pb,
                                            float* __restrict__ h) {
  int row = blockIdx.x;            // b*T + t
  int t = row & (T - 1);
  int d = threadIdx.x;
  __shared__ float xs[IN_DIM];
  if (threadIdx.x < IN_DIM) xs[threadIdx.x] = x[(size_t)row * IN_DIM + threadIdx.x];
  __syncthreads();
  float acc = pb[d];
#pragma unroll
  for (int i = 0; i < IN_DIM; ++i) acc += xs[i] * pw[i * D + d];
  int j = d >> 1;
  float div = __expf((float)(2 * j) * (-logf(10000.f) / (float)D));
  float ang = (float)t * div;
  acc += (d & 1) ? __cosf(ang) : __sinf(ang);
  h[(size_t)row * D + d] = acc;
}

// Fused K,V projection (R8-verified path) + qrow tail blocks (R1-verified path).
// grid = B*T/16 (kv) + B*U/2 (qrow), block = 256.
constexpr int KVB = B * T / 16;   // 8192
__global__ __launch_bounds__(256) void k_kvq(
    const float* __restrict__ h,
    const unsigned short* __restrict__ wkt,   // [128][128] f16 (n-major)
    const unsigned short* __restrict__ wvt,
    const int* __restrict__ idx,
    const float* __restrict__ wq,
    unsigned short* __restrict__ kbuf, unsigned short* __restrict__ vbuf,
    float* __restrict__ qs) {
  __shared__ unsigned short hsb[16 * 128];    // 4 KB; qrow path reuses as f32[2][128]
  const int tid = threadIdx.x;

  if (blockIdx.x >= KVB) {
    // ---- qrow path (R1-verified GEMV): 2 (b,u) pairs per block ----
    float* hs2 = (float*)hsb;                 // [2][128]
    int half = tid >> 7, d = tid & 127;
    int bu = (blockIdx.x - KVB) * 2 + half;   // < B*U (4352, even)
    int b = bu / U, u = bu - b * U;
    int t = idx[u];
    hs2[half * D + d] = h[((size_t)b * T + t) * D + d];
    __syncthreads();
    const float* hr = hs2 + half * D;
    float acc = 0.f;
    for (int k = 0; k < D; ++k) acc += hr[k] * wq[k * D + d];
    qs[(size_t)bu * D + d] = acc;
    return;
  }

  // ---- kv path (R8-verified, byte-identical) ----
  const int r0 = blockIdx.x * 16;
  {
    int m = tid >> 4, kc = tid & 15;
    const float* src = h + (size_t)(r0 + m) * D + kc * 8;
    float4 x0 = *(const float4*)src;
    float4 x1 = *(const float4*)(src + 4);
    f16x8 p;
    p[0] = (_Float16)x0.x; p[1] = (_Float16)x0.y;
    p[2] = (_Float16)x0.z; p[3] = (_Float16)x0.w;
    p[4] = (_Float16)x1.x; p[5] = (_Float16)x1.y;
    p[6] = (_Float16)x1.z; p[7] = (_Float16)x1.w;
    int byte = (m << 8) + (kc << 4);
    byte ^= (m & 7) << 4;
    *(f16x8*)((char*)hsb + byte) = p;
  }
  __syncthreads();
  const int wv = tid >> 6;
  const int l15 = tid & 15;
  const int lq = (tid & 63) >> 4;
  f16x8 afr[4];
#pragma unroll
  for (int ks = 0; ks < 4; ++ks) {
    int byte = (l15 << 8) + ks * 64 + (lq << 4);
    byte ^= (l15 & 7) << 4;
    afr[ks] = *(const f16x8*)((const char*)hsb + byte);
  }
  const unsigned short* wt = (wv < 2) ? wkt : wvt;
  unsigned short* outp = (wv < 2) ? kbuf : vbuf;
  const int cw = (wv & 1) * 64;
  f32x4 acc[4];
#pragma unroll
  for (int nt = 0; nt < 4; ++nt) acc[nt] = (f32x4){0.f, 0.f, 0.f, 0.f};
#pragma unroll
  for (int nt = 0; nt < 4; ++nt) {
    const unsigned short* wp = wt + (size_t)(cw + nt * 16 + l15) * 128 + lq * 8;
#pragma unroll
    for (int ks = 0; ks < 4; ++ks) {
      f16x8 bf = *(const f16x8*)(wp + ks * 32);
      acc[nt] = __builtin_amdgcn_mfma_f32_16x16x32_f16(afr[ks], bf, acc[nt], 0, 0, 0);
    }
  }
#pragma unroll
  for (int nt = 0; nt < 4; ++nt) {
    int col = cw + nt * 16 + l15;
    int hcol = col >> 4, dh = col & 15;
#pragma unroll
    for (int r = 0; r < 4; ++r) {
      int row = r0 + 4 * lq + r;             // C/D: row = 4*(lane>>4)+reg
      int b = row >> 10, t = row & (T - 1);
      outp[(((size_t)b * H + hcol) * T + t) * DH + dh] = f2h(acc[nt][r]);
    }
  }
}

// Attention v8 (R22-verified best): scores in registers, dot2 QK + pk_fma PV.
// grid = B*H*17, block = 256.
__global__ __launch_bounds__(256) void k_attn8(const float* __restrict__ qs,
                                               const unsigned short* __restrict__ kbuf,
                                               const unsigned short* __restrict__ vbuf,
                                               float* __restrict__ ctx) {
  constexpr int NWG = B * H * 17;
  int bid = blockIdx.x;
  int orig = (bid & 7) * (NWG / 8) + (bid >> 3);   // bijective XCD chunk (R9-verified)
  int up = orig % 17;
  int gb = orig / 17;
  int hh = gb & 7, b = gb >> 3;
  int u0 = up * 2;

  __shared__ h2 qh[2][8];
  __shared__ float red[8];
  __shared__ float redw[4][2][DH];
  const int tid = threadIdx.x;

  if (tid < 16) {
    int uu = tid >> 3, jj = tid & 7;
    const float* qp = qs + ((size_t)b * U + u0 + uu) * D + hh * DH + jj * 2;
    qh[uu][jj] = (h2){(_Float16)qp[0], (_Float16)qp[1]};
  }
  __syncthreads();
  const unsigned short* kg = kbuf + (size_t)gb * T * DH;
  const unsigned short* vg = vbuf + (size_t)gb * T * DH;

  h2 q0[8], q1[8];
#pragma unroll
  for (int j = 0; j < 8; ++j) { q0[j] = qh[0][j]; q1[j] = qh[1][j]; }

  // QK: scores stay in registers (4 t-steps per thread per u)
  float sc0[4], sc1[4];
  float lmax0 = -1e30f, lmax1 = -1e30f;
#pragma unroll
  for (int p = 0; p < 4; ++p) {
    int t = p * 256 + tid;
    const h2* k2 = (const h2*)(kg + t * DH);
    float s0 = 0.f, s1 = 0.f;
#pragma unroll
    for (int j = 0; j < 8; ++j) {
      h2 kv = k2[j];
      s0 = __builtin_amdgcn_fdot2(q0[j], kv, s0, false);
      s1 = __builtin_amdgcn_fdot2(q1[j], kv, s1, false);
    }
    s0 *= 0.25f; s1 *= 0.25f;        // 1/sqrt(16)
    sc0[p] = s0; sc1[p] = s1;
    lmax0 = fmaxf(lmax0, s0);
    lmax1 = fmaxf(lmax1, s1);
  }
  blockMax2(lmax0, lmax1, red);
  float lsum0 = 0.f, lsum1 = 0.f;
#pragma unroll
  for (int p = 0; p < 4; ++p) {
    sc0[p] = __expf(sc0[p] - lmax0);
    sc1[p] = __expf(sc1[p] - lmax1);
    lsum0 += sc0[p];
    lsum1 += sc1[p];
  }
  blockSum2(lsum0, lsum1, red);
  float inv0 = 1.f / lsum0;
  float inv1 = 1.f / lsum1;

  h2 p0[8], p1[8];
#pragma unroll
  for (int j = 0; j < 8; ++j) { p0[j] = (h2){0, 0}; p1[j] = (h2){0, 0}; }
#pragma unroll
  for (int p = 0; p < 4; ++p) {
    int t = p * 256 + tid;
    const h2* v2 = (const h2*)(vg + t * DH);
    _Float16 a0 = (_Float16)sc0[p], a1 = (_Float16)sc1[p];
    h2 a0h = (h2){a0, a0}, a1h = (h2){a1, a1};
#pragma unroll
    for (int j = 0; j < 8; ++j) {
      h2 vv = v2[j];
      p0[j] += a0h * vv;
      p1[j] += a1h * vv;
    }
  }
#pragma unroll
  for (int j = 0; j < 8; ++j) {
#pragma unroll
    for (int off = 32; off; off >>= 1) {
      p0[j] += shfl_xor_h2(p0[j], off);
      p1[j] += shfl_xor_h2(p1[j], off);
    }
  }
  const int wv = tid >> 6, lane = tid & 63;
  if (lane == 0) {
#pragma unroll
    for (int j = 0; j < 8; ++j) {
      redw[wv][0][2 * j]     = (float)p0[j][0];
      redw[wv][0][2 * j + 1] = (float)p0[j][1];
      redw[wv][1][2 * j]     = (float)p1[j][0];
      redw[wv][1][2 * j + 1] = (float)p1[j][1];
    }
  }
  __syncthreads();
  if (tid < 32) {
    int uu = tid >> 4, dh = tid & 15;
    float tot = redw[0][uu][dh] + redw[1][uu][dh] + redw[2][uu][dh] + redw[3][uu][dh];
    float inv = uu ? inv1 : inv0;
    ctx[((size_t)b * U + u0 + uu) * D + hh * DH + dh] = tot * inv;
  }
}

// Fused base+crow (+map fold, R20/R21-verified): grid B*(U+1)+8.
__global__ __launch_bounds__(D) void k_bc2(const float* __restrict__ ctx,
                                           const float* __restrict__ wo,
                                           const float* __restrict__ wob,
                                           const int* __restrict__ idx,
                                           float* __restrict__ ctxo,
                                           float* __restrict__ baseo,
                                           int* __restrict__ map) {
  int i = blockIdx.x;
  if (i >= B * (U + 1)) {
    int t = (i - B * (U + 1)) * D + threadIdx.x;   // 8 blocks x 128 = 1024
    int m = -1;
    for (int u = 0; u < U; ++u)
      if (idx[u] == t) m = u;
    map[t] = m;
    return;
  }
  int b = i / (U + 1), u = i - b * (U + 1);
  int d = threadIdx.x;
  __shared__ float cs[D];
  if (u < U) {
    cs[d] = ctx[((size_t)b * U + u) * D + d];
  } else {
    float s = 0.f;
    for (int uu = 0; uu < U; ++uu) s += ctx[((size_t)b * U + uu) * D + d];
    cs[d] = s * (1.f / (float)U);
  }
  __syncthreads();
  float acc = wob[d];
  for (int k = 0; k < D; ++k) acc += cs[k] * wo[k * D + d];
  if (u < U) ctxo[((size_t)b * U + u) * D + d] = acc;
  else       baseo[(size_t)b * D + d] = acc;
}

// Fused LN1 + FF + residual + LN2 (v5b, R17/R21-verified best: 148-151 us).
// 32 rows/block, 512 threads.
constexpr int RF2 = 32;
constexpr int YSS = 129;   // ys row stride (f32)
__global__ __launch_bounds__(512) void k_ff5b(
    const float* __restrict__ h,              // pre-LN1 h
    const float* __restrict__ ctxo,
    const float* __restrict__ baseo,
    const int* __restrict__ map,
    const float* __restrict__ g1,
    const float* __restrict__ b1n,
    const unsigned short* __restrict__ w1t,   // [512][128] f16 (n-major)
    const float* __restrict__ b1,
    const unsigned short* __restrict__ w2t,   // [128][512] f16 (n-major)
    const float* __restrict__ b2,
    const float* __restrict__ g2,
    const float* __restrict__ bb2,
    float* __restrict__ hout) {
  __shared__ unsigned short hsb[RF2 * 128];  // swizzled f16 LN1 output
  __shared__ unsigned short g16[RF2][520];   // gelu out; overlaid by f32 ys[32][129]

  const int tid = threadIdx.x;
  const int r0 = blockIdx.x * RF2;

  // ---- stage: y = h + attn_out; LN1 (16-lane groups); -> swizzled f16 hsb ----
  {
    int m = tid >> 4, kc = tid & 15;
    int row = r0 + m;
    int b = row >> 10, t = row & (T - 1);
    int u = map[t];
    const float* src = (u >= 0) ? ctxo + ((size_t)b * U + u) * D
                                : baseo + (size_t)b * D;
    const float* hp = h + (size_t)row * D + kc * 8;
    float4 x0 = *(const float4*)hp;
    float4 x1 = *(const float4*)(hp + 4);
    float4 a0 = *(const float4*)(src + kc * 8);
    float4 a1 = *(const float4*)(src + kc * 8 + 4);
    float y0 = x0.x + a0.x, y1 = x0.y + a0.y, y2 = x0.z + a0.z, y3 = x0.w + a0.w;
    float y4 = x1.x + a1.x, y5 = x1.y + a1.y, y6 = x1.z + a1.z, y7 = x1.w + a1.w;
    float s = y0 + y1 + y2 + y3 + y4 + y5 + y6 + y7;
#pragma unroll
    for (int off = 8; off; off >>= 1) s += __shfl_xor(s, off, 16);
    float mu = s * (1.f / D);
    float e0 = y0 - mu, e1 = y1 - mu, e2 = y2 - mu, e3 = y3 - mu;
    float e4 = y4 - mu, e5 = y5 - mu, e6 = y6 - mu, e7 = y7 - mu;
    float v2 = e0 * e0 + e1 * e1 + e2 * e2 + e3 * e3 +
               e4 * e4 + e5 * e5 + e6 * e6 + e7 * e7;
#pragma unroll
    for (int off = 8; off; off >>= 1) v2 += __shfl_xor(v2, off, 16);
    float inv = rsqrtf(v2 * (1.f / D) + 1e-5f);
    float4 gv0 = *(const float4*)(g1 + kc * 8);
    float4 gv1 = *(const float4*)(g1 + kc * 8 + 4);
    float4 bv0 = *(const float4*)(b1n + kc * 8);
    float4 bv1 = *(const float4*)(b1n + kc * 8 + 4);
    f16x8 p;
    p[0] = (_Float16)(e0 * inv * gv0.x + bv0.x);
    p[1] = (_Float16)(e1 * inv * gv0.y + bv0.y);
    p[2] = (_Float16)(e2 * inv * gv0.z + bv0.z);
    p[3] = (_Float16)(e3 * inv * gv0.w + bv0.w);
    p[4] = (_Float16)(e4 * inv * gv1.x + bv1.x);
    p[5] = (_Float16)(e5 * inv * gv1.y + bv1.y);
    p[6] = (_Float16)(e6 * inv * gv1.z + bv1.z);
    p[7] = (_Float16)(e7 * inv * gv1.w + bv1.w);
    int byte = (m << 8) + (kc << 4);
    byte ^= (m & 7) << 4;
    *(f16x8*)((char*)hsb + byte) = p;
  }
  __syncthreads();

  const int wv = tid >> 6;
  const int l15 = tid & 15;
  const int lq = (tid & 63) >> 4;

  f16x8 afr[2][4];
#pragma unroll
  for (int mt = 0; mt < 2; ++mt)
#pragma unroll
    for (int ks = 0; ks < 4; ++ks) {
      int m = mt * 16 + l15;
      int byte = (m << 8) + ks * 64 + (lq << 4);
      byte ^= (m & 7) << 4;
      afr[mt][ks] = *(const f16x8*)((const char*)hsb + byte);
    }

  // ---- phase 1 (R14-verified): g16 = f16(gelu(h1 @ w1 + b1)) ----
  for (int nt = 0; nt < 4; ++nt) {
    int n0 = wv * 64 + nt * 16;
    const unsigned short* wp = w1t + (size_t)(n0 + l15) * 128 + lq * 8;
    f32x4 a0 = (f32x4){0.f, 0.f, 0.f, 0.f};
    f32x4 a1 = (f32x4){0.f, 0.f, 0.f, 0.f};
#pragma unroll
    for (int ks = 0; ks < 4; ++ks) {
      f16x8 bf = *(const f16x8*)(wp + ks * 32);
      a0 = __builtin_amdgcn_mfma_f32_16x16x32_f16(afr[0][ks], bf, a0, 0, 0, 0);
      a1 = __builtin_amdgcn_mfma_f32_16x16x32_f16(afr[1][ks], bf, a1, 0, 0, 0);
    }
    float bcol = b1[n0 + l15];
#pragma unroll
    for (int r = 0; r < 4; ++r) {
      int row0 = 4 * lq + r;
      float v0 = a0[r] + bcol;
      v0 = 0.5f * v0 * (1.f + erf_fast(v0 * 0.70710678118654752f));
      g16[row0][n0 + l15] = f2h(v0);
      float v1 = a1[r] + bcol;
      v1 = 0.5f * v1 * (1.f + erf_fast(v1 * 0.70710678118654752f));
      g16[row0 + 16][n0 + l15] = f2h(v1);
    }
  }
  __syncthreads();

  // ---- phase 2 (R13 ILP split, R14-verified): C2 = G @ w2 ----
  f32x4 a2a[2], a2b[2];
  a2a[0] = (f32x4){0.f, 0.f, 0.f, 0.f};
  a2a[1] = (f32x4){0.f, 0.f, 0.f, 0.f};
  a2b[0] = (f32x4){0.f, 0.f, 0.f, 0.f};
  a2b[1] = (f32x4){0.f, 0.f, 0.f, 0.f};
  const int ncol = wv * 16 + l15;
  const unsigned short* wp2b = w2t + (size_t)ncol * 512;
  for (int ks = 0; ks < 8; ++ks) {
    int k0 = ks * 32 + lq * 8;
    int k1 = (ks + 8) * 32 + lq * 8;
    f16x8 x0 = *(const f16x8*)&g16[l15][k0];
    f16x8 x1 = *(const f16x8*)&g16[16 + l15][k0];
    f16x8 w0 = *(const f16x8*)(wp2b + k0);
    a2a[0] = __builtin_amdgcn_mfma_f32_16x16x32_f16(x0, w0, a2a[0], 0, 0, 0);
    a2a[1] = __builtin_amdgcn_mfma_f32_16x16x32_f16(x1, w0, a2a[1], 0, 0, 0);
    f16x8 y0 = *(const f16x8*)&g16[l15][k1];
    f16x8 y1 = *(const f16x8*)&g16[16 + l15][k1];
    f16x8 w1 = *(const f16x8*)(wp2b + k1);
    a2b[0] = __builtin_amdgcn_mfma_f32_16x16x32_f16(y0, w1, a2b[0], 0, 0, 0);
    a2b[1] = __builtin_amdgcn_mfma_f32_16x16x32_f16(y1, w1, a2b[1], 0, 0, 0);
  }
  f32x4 acc2[2];
#pragma unroll
  for (int mt = 0; mt < 2; ++mt) {
    acc2[mt][0] = a2a[mt][0] + a2b[mt][0];
    acc2[mt][1] = a2a[mt][1] + a2b[mt][1];
    acc2[mt][2] = a2a[mt][2] + a2b[mt][2];
    acc2[mt][3] = a2a[mt][3] + a2b[mt][3];
  }
  __syncthreads();   // all g16 reads done -> overlay ys

  float* ys = (float*)&g16[0][0];            // [32][129] f32 overlay
  {
    float bc = b2[ncol];
#pragma unroll
    for (int mt = 0; mt < 2; ++mt)
#pragma unroll
      for (int r = 0; r < 4; ++r) {
        int row = mt * 16 + 4 * lq + r;
        int byte = (row << 8) + ((ncol * 2) ^ ((row & 7) << 4));
        float h1 = (float)(*(const _Float16*)((const char*)hsb + byte));
        ys[row * YSS + ncol] = h1 + acc2[mt][r] + bc;
      }
  }
  __syncthreads();

  // ---- LN2 + output: barrier-free, each 16-lane group owns one row (R17-verified) ----
  {
    int row = tid >> 4, lane16 = tid & 15;
    const float* yr = ys + row * YSS;
    float yv[8];
    float s = 0.f;
#pragma unroll
    for (int j = 0; j < 8; ++j) {
      yv[j] = yr[lane16 + j * 16];
      s += yv[j];
    }
#pragma unroll
    for (int off = 8; off; off >>= 1) s += __shfl_xor(s, off, 16);
    float mu = s * (1.f / D);
    float v2 = 0.f;
#pragma unroll
    for (int j = 0; j < 8; ++j) {
      float e = yv[j] - mu;
      v2 += e * e;
    }
#pragma unroll
    for (int off = 8; off; off >>= 1) v2 += __shfl_xor(v2, off, 16);
    float inv = rsqrtf(v2 * (1.f / D) + 1e-5f);
    float* op = hout + (size_t)(r0 + row) * D;
#pragma unroll
    for (int j = 0; j < 8; ++j) {
      int dd = lane16 + j * 16;
      op[dd] = (yv[j] - mu) * inv * g2[dd] + bb2[dd];
    }
  }
}

// out[b] = LN(h[b,T-1,:]) @ head_w + head_wb
__global__ __launch_bounds__(D) void k_head(const float* __restrict__ h,
                                            const float* __restrict__ g,
                                            const float* __restrict__ bb,
                                            const float* __restrict__ hw,
                                            const float* __restrict__ hwb,
                                            float* __restrict__ out) {
  int b = blockIdx.x, d = threadIdx.x;
  float y = h[((size_t)b * T + (T - 1)) * D + d];
  __shared__ float red[2];
  float s = y;
  for (int off = 32; off; off >>= 1) s += __shfl_down(s, off);
  if ((threadIdx.x & 63) == 0) red[threadIdx.x >> 6] = s;
  __syncthreads();
  float m = (red[0] + red[1]) * (1.f / D);
  __syncthreads();
  float e = y - m;
  float v = e * e;
  for (int off = 32; off; off >>= 1) v += __shfl_down(v, off);
  if ((threadIdx.x & 63) == 0) red[threadIdx.x >> 6] = v;
  __syncthreads();
  float inv = rsqrtf((red[0] + red[1]) * (1.f / D) + 1e-5f);
  __syncthreads();
  float last = e * inv * g[d] + bb[d];
  float p = last * hw[d];
  for (int off = 32; off; off >>= 1) p += __shfl_down(p, off);
  if ((threadIdx.x & 63) == 0) red[threadIdx.x >> 6] = p;
  __syncthreads();
  if (threadIdx.x == 0) out[b] = red[0] + red[1] + hwb[0];
}

// ---------------- launch ----------------

extern "C" void kernel_launch(void* const* d_in, const int* in_sizes, int n_in,
                              void* d_out, int out_size, void* d_ws, size_t ws_size,
                              hipStream_t stream) {
  const float* x       = (const float*)d_in[0];
  const int*   idx     = (const int*)d_in[1];
  const float* proj_w  = (const float*)d_in[2];
  const float* proj_b  = (const float*)d_in[3];
  const float* wq      = (const float*)d_in[4];
  const float* wk      = (const float*)d_in[5];
  const float* wv      = (const float*)d_in[6];
  const float* wo      = (const float*)d_in[7];
  const float* wo_b    = (const float*)d_in[8];
  const float* ln1_g   = (const float*)d_in[9];
  const float* ln1_b   = (const float*)d_in[10];
  const float* ff1_w   = (const float*)d_in[11];
  const float* ff1_b   = (const float*)d_in[12];
  const float* ff2_w   = (const float*)d_in[13];
  const float* ff2_b   = (const float*)d_in[14];
  const float* ln2_g   = (const float*)d_in[15];
  const float* ln2_b   = (const float*)d_in[16];
  const float* head_g  = (const float*)d_in[17];
  const float* head_bb = (const float*)d_in[18];
  const float* head_w  = (const float*)d_in[19];
  const float* head_wb = (const float*)d_in[20];
  float* out = (float*)d_out;

  float* wsf  = (float*)d_ws;
  float* h    = wsf;
  float* kreg = h    + (size_t)B * T * D;   // region reused for f16 K
  float* vreg = kreg + (size_t)B * T * D;   // region reused for f16 V
  float* qs   = vreg + (size_t)B * T * D;
  float* ctx  = qs   + (size_t)B * U * D;
  float* ctxo = ctx  + (size_t)B * U * D;
  float* baseo= ctxo + (size_t)B * U * D;
  int*   map  = (int*)(baseo + (size_t)B * D);
  unsigned short* kbuf16 = (unsigned short*)kreg;    // [B][H][T][DH] f16
  unsigned short* vbuf16 = (unsigned short*)vreg;
  // dedicated per-layer f16 weight region (beyond map)
  unsigned short* wbuf = (unsigned short*)(map + 1024);
  const size_t PL = 16384 + 16384 + 65536 + 65536;   // ushorts per layer

  for (int l = 0; l < L; ++l) {
    unsigned short* wkT = wbuf + (size_t)l * PL;
    unsigned short* wvT = wkT + 16384;
    unsigned short* w1T = wvT + 16384;
    unsigned short* w2T = w1T + 65536;
    k_prep_all<<<640, 256, 0, stream>>>(wk + (size_t)l * D * D,
                                        wv + (size_t)l * D * D,
                                        ff1_w + (size_t)l * D * FF,
                                        ff2_w + (size_t)l * FF * D,
                                        wkT, wvT, w1T, w2T);
  }

  k_proj<<<B * T, D, 0, stream>>>(x, proj_w, proj_b, h);

  for (int l = 0; l < L; ++l) {
    const float* wq_l = wq + (size_t)l * D * D;
    const float* wo_l = wo + (size_t)l * D * D;
    const int*   idx_l = idx + l * U;
    unsigned short* wkT = wbuf + (size_t)l * PL;
    unsigned short* wvT = wkT + 16384;
    unsigned short* w1T = wvT + 16384;
    unsigned short* w2T = w1T + 65536;

    k_kvq<<<KVB + B * U / 2, 256, 0, stream>>>(h, wkT, wvT, idx_l, wq_l,
                                               kbuf16, vbuf16, qs);
    k_attn8<<<B * H * 17, 256, 0, stream>>>(qs, kbuf16, vbuf16, ctx);
    k_bc2<<<B * (U + 1) + 8, D, 0, stream>>>(ctx, wo_l, wo_b + l * D, idx_l,
                                             ctxo, baseo, map);
    k_ff5b<<<B * T / RF2, 512, 0, stream>>>(h, ctxo, baseo, map,
                                            ln1_g + l * D, ln1_b + l * D,
                                            w1T, ff1_b + l * FF,
                                            w2T, ff2_b + l * D,
                                            ln2_g + l * D, ln2_b + l * D, h);
  }

  k_head<<<B, D, 0, stream>>>(h, head_g, head_bb, head_w, head_wb, out);
}

// Round 26
// 732.560 us; speedup vs baseline: 1.0266x; 1.0069x over previous
//
#include <hip/hip_runtime.h>
#include <math.h>

// Problem constants
constexpr int B  = 128;
constexpr int T  = 1024;
constexpr int IN_DIM = 32;
constexpr int D  = 128;
constexpr int H  = 8;
constexpr int DH = 16;   // D/H
constexpr int L  = 2;
constexpr int U  = 34;   // int(5*ln(1025))
constexpr int FF = 512;  // 4*D

typedef __attribute__((ext_vector_type(8))) _Float16 f16x8;
typedef __attribute__((ext_vector_type(2))) _Float16 h2;
typedef __attribute__((ext_vector_type(4))) float f32x4;

__device__ __forceinline__ unsigned short f2h(float x) {
  union { _Float16 h; unsigned short u; } v;
  v.h = (_Float16)x;
  return v.u;
}

__device__ __forceinline__ h2 shfl_xor_h2(h2 v, int off) {
  union { h2 h; int i; } u;
  u.h = v;
  u.i = __shfl_xor(u.i, off);
  return u.h;
}

// Branch-free erf, Abramowitz-Stegun 7.1.26 (|err| <= 1.5e-7)  (R10-verified)
__device__ __forceinline__ float erf_fast(float x) {
  float a = fabsf(x);
  float t = __builtin_amdgcn_rcpf(fmaf(0.3275911f, a, 1.f));
  float y = t * (0.254829592f +
            t * (-0.284496736f +
            t * (1.421413741f +
            t * (-1.453152027f +
            t * 1.061405429f))));
  float r = 1.f - y * __expf(-a * a);
  return copysignf(r, x);
}

// ---------------- helpers ----------------

// Paired block reductions (one barrier pair for two values)  (R15-verified)
__device__ __forceinline__ void blockMax2(float& a, float& b, float* red) {
  for (int off = 32; off; off >>= 1) {
    a = fmaxf(a, __shfl_down(a, off));
    b = fmaxf(b, __shfl_down(b, off));
  }
  if ((threadIdx.x & 63) == 0) {
    red[threadIdx.x >> 6] = a;
    red[4 + (threadIdx.x >> 6)] = b;
  }
  __syncthreads();
  a = fmaxf(fmaxf(red[0], red[1]), fmaxf(red[2], red[3]));
  b = fmaxf(fmaxf(red[4], red[5]), fmaxf(red[6], red[7]));
  __syncthreads();
}

__device__ __forceinline__ void blockSum2(float& a, float& b, float* red) {
  for (int off = 32; off; off >>= 1) {
    a += __shfl_down(a, off);
    b += __shfl_down(b, off);
  }
  if ((threadIdx.x & 63) == 0) {
    red[threadIdx.x >> 6] = a;
    red[4 + (threadIdx.x >> 6)] = b;
  }
  __syncthreads();
  a = red[0] + red[1] + red[2] + red[3];
  b = red[4] + red[5] + red[6] + red[7];
  __syncthreads();
}

// ---------------- kernels ----------------

// Fused prologue: proj (4096 blocks, 2 rows each) + weight-prep for both layers
// (2 x 640 blocks). All paths independent.
constexpr int PROJB = B * T / 2 / 4;      // wait—computed below; use direct constant
// proj blocks: B*T rows / 2 rows per block = 65536? No: B*T = 131072 rows; but
// original k_proj used one 128-thr block per row (131072 blocks!). Actually
// grid was B*T = 131072 blocks of 128 threads. 2 rows per 256-thr block ->
// 65536 blocks. Keep that.
constexpr int NPROJ = B * T / 2;          // 65536 blocks, 256 thr, 2 rows each
constexpr int NPREP = 640;                // per layer
__global__ __launch_bounds__(256) void k_pp(
    const float* __restrict__ x,
    const float* __restrict__ pw,
    const float* __restrict__ pb,
    float* __restrict__ h,
    const float* __restrict__ wk,         // [L][128][128]
    const float* __restrict__ wv,
    const float* __restrict__ ff1_w,      // [L][128][512]
    const float* __restrict__ ff2_w,      // [L][512][128]
    unsigned short* __restrict__ wbuf) {  // per-layer {wkT,wvT,w1T,w2T}
  const int tid = threadIdx.x;
  if (blockIdx.x < NPROJ) {
    // ---- proj path (R13-verified body, 2 rows/block) ----
    int half = tid >> 7, d = tid & 127;
    int row = blockIdx.x * 2 + half;      // b*T + t
    int t = row & (T - 1);
    __shared__ float xs[2][IN_DIM];
    if (d < IN_DIM) xs[half][d] = x[(size_t)row * IN_DIM + d];
    __syncthreads();
    float acc = pb[d];
#pragma unroll
    for (int i = 0; i < IN_DIM; ++i) acc += xs[half][i] * pw[i * D + d];
    int j = d >> 1;
    float div = __expf((float)(2 * j) * (-logf(10000.f) / (float)D));
    float ang = (float)t * div;
    acc += (d & 1) ? __cosf(ang) : __sinf(ang);
    h[(size_t)row * D + d] = acc;
    return;
  }
  // ---- prep path (R13-verified indexing), layer l ----
  int pb2 = blockIdx.x - NPROJ;           // 0..1279
  int l = pb2 / NPREP;
  const size_t PL = 16384 + 16384 + 65536 + 65536;
  unsigned short* wkT = wbuf + (size_t)l * PL;
  unsigned short* wvT = wkT + 16384;
  unsigned short* w1T = wvT + 16384;
  unsigned short* w2T = w1T + 65536;
  const float* wk_l = wk + (size_t)l * D * D;
  const float* wv_l = wv + (size_t)l * D * D;
  const float* w1_l = ff1_w + (size_t)l * D * FF;
  const float* w2_l = ff2_w + (size_t)l * FF * D;
  int idx = (pb2 - l * NPREP) * 256 + tid;
  if (idx < 16384) {
    int n = idx >> 7, k = idx & 127;
    wkT[idx] = f2h(wk_l[k * 128 + n]);
  } else if (idx < 32768) {
    int j = idx - 16384;
    int n = j >> 7, k = j & 127;
    wvT[j] = f2h(wv_l[k * 128 + n]);
  } else if (idx < 98304) {
    int j = idx - 32768;
    int n = j >> 7, k = j & 127;
    w1T[j] = f2h(w1_l[k * 512 + n]);
  } else if (idx < 163840) {
    int j = idx - 98304;
    int n = j >> 9, k = j & 511;
    w2T[j] = f2h(w2_l[k * 128 + n]);
  }
}

// Fused K,V projection (R8-verified path) + qrow tail blocks (R1-verified path).
// grid = B*T/16 (kv) + B*U/2 (qrow), block = 256.  (R25-verified)
constexpr int KVB = B * T / 16;   // 8192
__global__ __launch_bounds__(256) void k_kvq(
    const float* __restrict__ h,
    const unsigned short* __restrict__ wkt,   // [128][128] f16 (n-major)
    const unsigned short* __restrict__ wvt,
    const int* __restrict__ idx,
    const float* __restrict__ wq,
    unsigned short* __restrict__ kbuf, unsigned short* __restrict__ vbuf,
    float* __restrict__ qs) {
  __shared__ unsigned short hsb[16 * 128];    // 4 KB; qrow path reuses as f32[2][128]
  const int tid = threadIdx.x;

  if (blockIdx.x >= KVB) {
    // ---- qrow path (R1-verified GEMV): 2 (b,u) pairs per block ----
    float* hs2 = (float*)hsb;                 // [2][128]
    int half = tid >> 7, d = tid & 127;
    int bu = (blockIdx.x - KVB) * 2 + half;   // < B*U (4352, even)
    int b = bu / U, u = bu - b * U;
    int t = idx[u];
    hs2[half * D + d] = h[((size_t)b * T + t) * D + d];
    __syncthreads();
    const float* hr = hs2 + half * D;
    float acc = 0.f;
    for (int k = 0; k < D; ++k) acc += hr[k] * wq[k * D + d];
    qs[(size_t)bu * D + d] = acc;
    return;
  }

  // ---- kv path (R8-verified, byte-identical) ----
  const int r0 = blockIdx.x * 16;
  {
    int m = tid >> 4, kc = tid & 15;
    const float* src = h + (size_t)(r0 + m) * D + kc * 8;
    float4 x0 = *(const float4*)src;
    float4 x1 = *(const float4*)(src + 4);
    f16x8 p;
    p[0] = (_Float16)x0.x; p[1] = (_Float16)x0.y;
    p[2] = (_Float16)x0.z; p[3] = (_Float16)x0.w;
    p[4] = (_Float16)x1.x; p[5] = (_Float16)x1.y;
    p[6] = (_Float16)x1.z; p[7] = (_Float16)x1.w;
    int byte = (m << 8) + (kc << 4);
    byte ^= (m & 7) << 4;
    *(f16x8*)((char*)hsb + byte) = p;
  }
  __syncthreads();
  const int wv = tid >> 6;
  const int l15 = tid & 15;
  const int lq = (tid & 63) >> 4;
  f16x8 afr[4];
#pragma unroll
  for (int ks = 0; ks < 4; ++ks) {
    int byte = (l15 << 8) + ks * 64 + (lq << 4);
    byte ^= (l15 & 7) << 4;
    afr[ks] = *(const f16x8*)((const char*)hsb + byte);
  }
  const unsigned short* wt = (wv < 2) ? wkt : wvt;
  unsigned short* outp = (wv < 2) ? kbuf : vbuf;
  const int cw = (wv & 1) * 64;
  f32x4 acc[4];
#pragma unroll
  for (int nt = 0; nt < 4; ++nt) acc[nt] = (f32x4){0.f, 0.f, 0.f, 0.f};
#pragma unroll
  for (int nt = 0; nt < 4; ++nt) {
    const unsigned short* wp = wt + (size_t)(cw + nt * 16 + l15) * 128 + lq * 8;
#pragma unroll
    for (int ks = 0; ks < 4; ++ks) {
      f16x8 bf = *(const f16x8*)(wp + ks * 32);
      acc[nt] = __builtin_amdgcn_mfma_f32_16x16x32_f16(afr[ks], bf, acc[nt], 0, 0, 0);
    }
  }
#pragma unroll
  for (int nt = 0; nt < 4; ++nt) {
    int col = cw + nt * 16 + l15;
    int hcol = col >> 4, dh = col & 15;
#pragma unroll
    for (int r = 0; r < 4; ++r) {
      int row = r0 + 4 * lq + r;             // C/D: row = 4*(lane>>4)+reg
      int b = row >> 10, t = row & (T - 1);
      outp[(((size_t)b * H + hcol) * T + t) * DH + dh] = f2h(acc[nt][r]);
    }
  }
}

// Attention v8 (R22-verified best): scores in registers, dot2 QK + pk_fma PV.
// grid = B*H*17, block = 256.
__global__ __launch_bounds__(256) void k_attn8(const float* __restrict__ qs,
                                               const unsigned short* __restrict__ kbuf,
                                               const unsigned short* __restrict__ vbuf,
                                               float* __restrict__ ctx) {
  constexpr int NWG = B * H * 17;
  int bid = blockIdx.x;
  int orig = (bid & 7) * (NWG / 8) + (bid >> 3);   // bijective XCD chunk (R9-verified)
  int up = orig % 17;
  int gb = orig / 17;
  int hh = gb & 7, b = gb >> 3;
  int u0 = up * 2;

  __shared__ h2 qh[2][8];
  __shared__ float red[8];
  __shared__ float redw[4][2][DH];
  const int tid = threadIdx.x;

  if (tid < 16) {
    int uu = tid >> 3, jj = tid & 7;
    const float* qp = qs + ((size_t)b * U + u0 + uu) * D + hh * DH + jj * 2;
    qh[uu][jj] = (h2){(_Float16)qp[0], (_Float16)qp[1]};
  }
  __syncthreads();
  const unsigned short* kg = kbuf + (size_t)gb * T * DH;
  const unsigned short* vg = vbuf + (size_t)gb * T * DH;

  h2 q0[8], q1[8];
#pragma unroll
  for (int j = 0; j < 8; ++j) { q0[j] = qh[0][j]; q1[j] = qh[1][j]; }

  // QK: scores stay in registers (4 t-steps per thread per u)
  float sc0[4], sc1[4];
  float lmax0 = -1e30f, lmax1 = -1e30f;
#pragma unroll
  for (int p = 0; p < 4; ++p) {
    int t = p * 256 + tid;
    const h2* k2 = (const h2*)(kg + t * DH);
    float s0 = 0.f, s1 = 0.f;
#pragma unroll
    for (int j = 0; j < 8; ++j) {
      h2 kv = k2[j];
      s0 = __builtin_amdgcn_fdot2(q0[j], kv, s0, false);
      s1 = __builtin_amdgcn_fdot2(q1[j], kv, s1, false);
    }
    s0 *= 0.25f; s1 *= 0.25f;        // 1/sqrt(16)
    sc0[p] = s0; sc1[p] = s1;
    lmax0 = fmaxf(lmax0, s0);
    lmax1 = fmaxf(lmax1, s1);
  }
  blockMax2(lmax0, lmax1, red);
  float lsum0 = 0.f, lsum1 = 0.f;
#pragma unroll
  for (int p = 0; p < 4; ++p) {
    sc0[p] = __expf(sc0[p] - lmax0);
    sc1[p] = __expf(sc1[p] - lmax1);
    lsum0 += sc0[p];
    lsum1 += sc1[p];
  }
  blockSum2(lsum0, lsum1, red);
  float inv0 = 1.f / lsum0;
  float inv1 = 1.f / lsum1;

  h2 p0[8], p1[8];
#pragma unroll
  for (int j = 0; j < 8; ++j) { p0[j] = (h2){0, 0}; p1[j] = (h2){0, 0}; }
#pragma unroll
  for (int p = 0; p < 4; ++p) {
    int t = p * 256 + tid;
    const h2* v2 = (const h2*)(vg + t * DH);
    _Float16 a0 = (_Float16)sc0[p], a1 = (_Float16)sc1[p];
    h2 a0h = (h2){a0, a0}, a1h = (h2){a1, a1};
#pragma unroll
    for (int j = 0; j < 8; ++j) {
      h2 vv = v2[j];
      p0[j] += a0h * vv;
      p1[j] += a1h * vv;
    }
  }
#pragma unroll
  for (int j = 0; j < 8; ++j) {
#pragma unroll
    for (int off = 32; off; off >>= 1) {
      p0[j] += shfl_xor_h2(p0[j], off);
      p1[j] += shfl_xor_h2(p1[j], off);
    }
  }
  const int wv = tid >> 6, lane = tid & 63;
  if (lane == 0) {
#pragma unroll
    for (int j = 0; j < 8; ++j) {
      redw[wv][0][2 * j]     = (float)p0[j][0];
      redw[wv][0][2 * j + 1] = (float)p0[j][1];
      redw[wv][1][2 * j]     = (float)p1[j][0];
      redw[wv][1][2 * j + 1] = (float)p1[j][1];
    }
  }
  __syncthreads();
  if (tid < 32) {
    int uu = tid >> 4, dh = tid & 15;
    float tot = redw[0][uu][dh] + redw[1][uu][dh] + redw[2][uu][dh] + redw[3][uu][dh];
    float inv = uu ? inv1 : inv0;
    ctx[((size_t)b * U + u0 + uu) * D + hh * DH + dh] = tot * inv;
  }
}

// Fused base+crow (+map fold, R20/R21-verified): grid B*(U+1)+8.
__global__ __launch_bounds__(D) void k_bc2(const float* __restrict__ ctx,
                                           const float* __restrict__ wo,
                                           const float* __restrict__ wob,
                                           const int* __restrict__ idx,
                                           float* __restrict__ ctxo,
                                           float* __restrict__ baseo,
                                           int* __restrict__ map) {
  int i = blockIdx.x;
  if (i >= B * (U + 1)) {
    int t = (i - B * (U + 1)) * D + threadIdx.x;   // 8 blocks x 128 = 1024
    int m = -1;
    for (int u = 0; u < U; ++u)
      if (idx[u] == t) m = u;
    map[t] = m;
    return;
  }
  int b = i / (U + 1), u = i - b * (U + 1);
  int d = threadIdx.x;
  __shared__ float cs[D];
  if (u < U) {
    cs[d] = ctx[((size_t)b * U + u) * D + d];
  } else {
    float s = 0.f;
    for (int uu = 0; uu < U; ++uu) s += ctx[((size_t)b * U + uu) * D + d];
    cs[d] = s * (1.f / (float)U);
  }
  __syncthreads();
  float acc = wob[d];
  for (int k = 0; k < D; ++k) acc += cs[k] * wo[k * D + d];
  if (u < U) ctxo[((size_t)b * U + u) * D + d] = acc;
  else       baseo[(size_t)b * D + d] = acc;
}

// Fused LN1 + FF + residual + LN2 (v5b, R17/R21-verified best: 148-151 us).
// 32 rows/block, 512 threads.
constexpr int RF2 = 32;
constexpr int YSS = 129;   // ys row stride (f32)
__global__ __launch_bounds__(512) void k_ff5b(
    const float* __restrict__ h,              // pre-LN1 h
    const float* __restrict__ ctxo,
    const float* __restrict__ baseo,
    const int* __restrict__ map,
    const float* __restrict__ g1,
    const float* __restrict__ b1n,
    const unsigned short* __restrict__ w1t,   // [512][128] f16 (n-major)
    const float* __restrict__ b1,
    const unsigned short* __restrict__ w2t,   // [128][512] f16 (n-major)
    const float* __restrict__ b2,
    const float* __restrict__ g2,
    const float* __restrict__ bb2,
    float* __restrict__ hout) {
  __shared__ unsigned short hsb[RF2 * 128];  // swizzled f16 LN1 output
  __shared__ unsigned short g16[RF2][520];   // gelu out; overlaid by f32 ys[32][129]

  const int tid = threadIdx.x;
  const int r0 = blockIdx.x * RF2;

  // ---- stage: y = h + attn_out; LN1 (16-lane groups); -> swizzled f16 hsb ----
  {
    int m = tid >> 4, kc = tid & 15;
    int row = r0 + m;
    int b = row >> 10, t = row & (T - 1);
    int u = map[t];
    const float* src = (u >= 0) ? ctxo + ((size_t)b * U + u) * D
                                : baseo + (size_t)b * D;
    const float* hp = h + (size_t)row * D + kc * 8;
    float4 x0 = *(const float4*)hp;
    float4 x1 = *(const float4*)(hp + 4);
    float4 a0 = *(const float4*)(src + kc * 8);
    float4 a1 = *(const float4*)(src + kc * 8 + 4);
    float y0 = x0.x + a0.x, y1 = x0.y + a0.y, y2 = x0.z + a0.z, y3 = x0.w + a0.w;
    float y4 = x1.x + a1.x, y5 = x1.y + a1.y, y6 = x1.z + a1.z, y7 = x1.w + a1.w;
    float s = y0 + y1 + y2 + y3 + y4 + y5 + y6 + y7;
#pragma unroll
    for (int off = 8; off; off >>= 1) s += __shfl_xor(s, off, 16);
    float mu = s * (1.f / D);
    float e0 = y0 - mu, e1 = y1 - mu, e2 = y2 - mu, e3 = y3 - mu;
    float e4 = y4 - mu, e5 = y5 - mu, e6 = y6 - mu, e7 = y7 - mu;
    float v2 = e0 * e0 + e1 * e1 + e2 * e2 + e3 * e3 +
               e4 * e4 + e5 * e5 + e6 * e6 + e7 * e7;
#pragma unroll
    for (int off = 8; off; off >>= 1) v2 += __shfl_xor(v2, off, 16);
    float inv = rsqrtf(v2 * (1.f / D) + 1e-5f);
    float4 gv0 = *(const float4*)(g1 + kc * 8);
    float4 gv1 = *(const float4*)(g1 + kc * 8 + 4);
    float4 bv0 = *(const float4*)(b1n + kc * 8);
    float4 bv1 = *(const float4*)(b1n + kc * 8 + 4);
    f16x8 p;
    p[0] = (_Float16)(e0 * inv * gv0.x + bv0.x);
    p[1] = (_Float16)(e1 * inv * gv0.y + bv0.y);
    p[2] = (_Float16)(e2 * inv * gv0.z + bv0.z);
    p[3] = (_Float16)(e3 * inv * gv0.w + bv0.w);
    p[4] = (_Float16)(e4 * inv * gv1.x + bv1.x);
    p[5] = (_Float16)(e5 * inv * gv1.y + bv1.y);
    p[6] = (_Float16)(e6 * inv * gv1.z + bv1.z);
    p[7] = (_Float16)(e7 * inv * gv1.w + bv1.w);
    int byte = (m << 8) + (kc << 4);
    byte ^= (m & 7) << 4;
    *(f16x8*)((char*)hsb + byte) = p;
  }
  __syncthreads();

  const int wv = tid >> 6;
  const int l15 = tid & 15;
  const int lq = (tid & 63) >> 4;

  f16x8 afr[2][4];
#pragma unroll
  for (int mt = 0; mt < 2; ++mt)
#pragma unroll
    for (int ks = 0; ks < 4; ++ks) {
      int m = mt * 16 + l15;
      int byte = (m << 8) + ks * 64 + (lq << 4);
      byte ^= (m & 7) << 4;
      afr[mt][ks] = *(const f16x8*)((const char*)hsb + byte);
    }

  // ---- phase 1 (R14-verified): g16 = f16(gelu(h1 @ w1 + b1)) ----
  for (int nt = 0; nt < 4; ++nt) {
    int n0 = wv * 64 + nt * 16;
    const unsigned short* wp = w1t + (size_t)(n0 + l15) * 128 + lq * 8;
    f32x4 a0 = (f32x4){0.f, 0.f, 0.f, 0.f};
    f32x4 a1 = (f32x4){0.f, 0.f, 0.f, 0.f};
#pragma unroll
    for (int ks = 0; ks < 4; ++ks) {
      f16x8 bf = *(const f16x8*)(wp + ks * 32);
      a0 = __builtin_amdgcn_mfma_f32_16x16x32_f16(afr[0][ks], bf, a0, 0, 0, 0);
      a1 = __builtin_amdgcn_mfma_f32_16x16x32_f16(afr[1][ks], bf, a1, 0, 0, 0);
    }
    float bcol = b1[n0 + l15];
#pragma unroll
    for (int r = 0; r < 4; ++r) {
      int row0 = 4 * lq + r;
      float v0 = a0[r] + bcol;
      v0 = 0.5f * v0 * (1.f + erf_fast(v0 * 0.70710678118654752f));
      g16[row0][n0 + l15] = f2h(v0);
      float v1 = a1[r] + bcol;
      v1 = 0.5f * v1 * (1.f + erf_fast(v1 * 0.70710678118654752f));
      g16[row0 + 16][n0 + l15] = f2h(v1);
    }
  }
  __syncthreads();

  // ---- phase 2 (R13 ILP split, R14-verified): C2 = G @ w2 ----
  f32x4 a2a[2], a2b[2];
  a2a[0] = (f32x4){0.f, 0.f, 0.f, 0.f};
  a2a[1] = (f32x4){0.f, 0.f, 0.f, 0.f};
  a2b[0] = (f32x4){0.f, 0.f, 0.f, 0.f};
  a2b[1] = (f32x4){0.f, 0.f, 0.f, 0.f};
  const int ncol = wv * 16 + l15;
  const unsigned short* wp2b = w2t + (size_t)ncol * 512;
  for (int ks = 0; ks < 8; ++ks) {
    int k0 = ks * 32 + lq * 8;
    int k1 = (ks + 8) * 32 + lq * 8;
    f16x8 x0 = *(const f16x8*)&g16[l15][k0];
    f16x8 x1 = *(const f16x8*)&g16[16 + l15][k0];
    f16x8 w0 = *(const f16x8*)(wp2b + k0);
    a2a[0] = __builtin_amdgcn_mfma_f32_16x16x32_f16(x0, w0, a2a[0], 0, 0, 0);
    a2a[1] = __builtin_amdgcn_mfma_f32_16x16x32_f16(x1, w0, a2a[1], 0, 0, 0);
    f16x8 y0 = *(const f16x8*)&g16[l15][k1];
    f16x8 y1 = *(const f16x8*)&g16[16 + l15][k1];
    f16x8 w1 = *(const f16x8*)(wp2b + k1);
    a2b[0] = __builtin_amdgcn_mfma_f32_16x16x32_f16(y0, w1, a2b[0], 0, 0, 0);
    a2b[1] = __builtin_amdgcn_mfma_f32_16x16x32_f16(y1, w1, a2b[1], 0, 0, 0);
  }
  f32x4 acc2[2];
#pragma unroll
  for (int mt = 0; mt < 2; ++mt) {
    acc2[mt][0] = a2a[mt][0] + a2b[mt][0];
    acc2[mt][1] = a2a[mt][1] + a2b[mt][1];
    acc2[mt][2] = a2a[mt][2] + a2b[mt][2];
    acc2[mt][3] = a2a[mt][3] + a2b[mt][3];
  }
  __syncthreads();   // all g16 reads done -> overlay ys

  float* ys = (float*)&g16[0][0];            // [32][129] f32 overlay
  {
    float bc = b2[ncol];
#pragma unroll
    for (int mt = 0; mt < 2; ++mt)
#pragma unroll
      for (int r = 0; r < 4; ++r) {
        int row = mt * 16 + 4 * lq + r;
        int byte = (row << 8) + ((ncol * 2) ^ ((row & 7) << 4));
        float h1 = (float)(*(const _Float16*)((const char*)hsb + byte));
        ys[row * YSS + ncol] = h1 + acc2[mt][r] + bc;
      }
  }
  __syncthreads();

  // ---- LN2 + output: barrier-free, each 16-lane group owns one row (R17-verified) ----
  {
    int row = tid >> 4, lane16 = tid & 15;
    const float* yr = ys + row * YSS;
    float yv[8];
    float s = 0.f;
#pragma unroll
    for (int j = 0; j < 8; ++j) {
      yv[j] = yr[lane16 + j * 16];
      s += yv[j];
    }
#pragma unroll
    for (int off = 8; off; off >>= 1) s += __shfl_xor(s, off, 16);
    float mu = s * (1.f / D);
    float v2 = 0.f;
#pragma unroll
    for (int j = 0; j < 8; ++j) {
      float e = yv[j] - mu;
      v2 += e * e;
    }
#pragma unroll
    for (int off = 8; off; off >>= 1) v2 += __shfl_xor(v2, off, 16);
    float inv = rsqrtf(v2 * (1.f / D) + 1e-5f);
    float* op = hout + (size_t)(r0 + row) * D;
#pragma unroll
    for (int j = 0; j < 8; ++j) {
      int dd = lane16 + j * 16;
      op[dd] = (yv[j] - mu) * inv * g2[dd] + bb2[dd];
    }
  }
}

// out[b] = LN(h[b,T-1,:]) @ head_w + head_wb
__global__ __launch_bounds__(D) void k_head(const float* __restrict__ h,
                                            const float* __restrict__ g,
                                            const float* __restrict__ bb,
                                            const float* __restrict__ hw,
                                            const float* __restrict__ hwb,
                                            float* __restrict__ out) {
  int b = blockIdx.x, d = threadIdx.x;
  float y = h[((size_t)b * T + (T - 1)) * D + d];
  __shared__ float red[2];
  float s = y;
  for (int off = 32; off; off >>= 1) s += __shfl_down(s, off);
  if ((threadIdx.x & 63) == 0) red[threadIdx.x >> 6] = s;
  __syncthreads();
  float m = (red[0] + red[1]) * (1.f / D);
  __syncthreads();
  float e = y - m;
  float v = e * e;
  for (int off = 32; off; off >>= 1) v += __shfl_down(v, off);
  if ((threadIdx.x & 63) == 0) red[threadIdx.x >> 6] = v;
  __syncthreads();
  float inv = rsqrtf((red[0] + red[1]) * (1.f / D) + 1e-5f);
  __syncthreads();
  float last = e * inv * g[d] + bb[d];
  float p = last * hw[d];
  for (int off = 32; off; off >>= 1) p += __shfl_down(p, off);
  if ((threadIdx.x & 63) == 0) red[threadIdx.x >> 6] = p;
  __syncthreads();
  if (threadIdx.x == 0) out[b] = red[0] + red[1] + hwb[0];
}

// ---------------- launch ----------------

extern "C" void kernel_launch(void* const* d_in, const int* in_sizes, int n_in,
                              void* d_out, int out_size, void* d_ws, size_t ws_size,
                              hipStream_t stream) {
  const float* x       = (const float*)d_in[0];
  const int*   idx     = (const int*)d_in[1];
  const float* proj_w  = (const float*)d_in[2];
  const float* proj_b  = (const float*)d_in[3];
  const float* wq      = (const float*)d_in[4];
  const float* wk      = (const float*)d_in[5];
  const float* wv      = (const float*)d_in[6];
  const float* wo      = (const float*)d_in[7];
  const float* wo_b    = (const float*)d_in[8];
  const float* ln1_g   = (const float*)d_in[9];
  const float* ln1_b   = (const float*)d_in[10];
  const float* ff1_w   = (const float*)d_in[11];
  const float* ff1_b   = (const float*)d_in[12];
  const float* ff2_w   = (const float*)d_in[13];
  const float* ff2_b   = (const float*)d_in[14];
  const float* ln2_g   = (const float*)d_in[15];
  const float* ln2_b   = (const float*)d_in[16];
  const float* head_g  = (const float*)d_in[17];
  const float* head_bb = (const float*)d_in[18];
  const float* head_w  = (const float*)d_in[19];
  const float* head_wb = (const float*)d_in[20];
  float* out = (float*)d_out;

  float* wsf  = (float*)d_ws;
  float* h    = wsf;
  float* kreg = h    + (size_t)B * T * D;   // region reused for f16 K
  float* vreg = kreg + (size_t)B * T * D;   // region reused for f16 V
  float* qs   = vreg + (size_t)B * T * D;
  float* ctx  = qs   + (size_t)B * U * D;
  float* ctxo = ctx  + (size_t)B * U * D;
  float* baseo= ctxo + (size_t)B * U * D;
  int*   map  = (int*)(baseo + (size_t)B * D);
  unsigned short* kbuf16 = (unsigned short*)kreg;    // [B][H][T][DH] f16
  unsigned short* vbuf16 = (unsigned short*)vreg;
  // dedicated per-layer f16 weight region (beyond map)
  unsigned short* wbuf = (unsigned short*)(map + 1024);
  const size_t PL = 16384 + 16384 + 65536 + 65536;   // ushorts per layer

  // Fused prologue: proj + both layers' weight prep in one launch
  k_pp<<<NPROJ + 2 * NPREP, 256, 0, stream>>>(x, proj_w, proj_b, h,
                                              wk, wv, ff1_w, ff2_w, wbuf);

  for (int l = 0; l < L; ++l) {
    const float* wq_l = wq + (size_t)l * D * D;
    const float* wo_l = wo + (size_t)l * D * D;
    const int*   idx_l = idx + l * U;
    unsigned short* wkT = wbuf + (size_t)l * PL;
    unsigned short* wvT = wkT + 16384;
    unsigned short* w1T = wvT + 16384;
    unsigned short* w2T = w1T + 65536;

    k_kvq<<<KVB + B * U / 2, 256, 0, stream>>>(h, wkT, wvT, idx_l, wq_l,
                                               kbuf16, vbuf16, qs);
    k_attn8<<<B * H * 17, 256, 0, stream>>>(qs, kbuf16, vbuf16, ctx);
    k_bc2<<<B * (U + 1) + 8, D, 0, stream>>>(ctx, wo_l, wo_b + l * D, idx_l,
                                             ctxo, baseo, map);
    k_ff5b<<<B * T / RF2, 512, 0, stream>>>(h, ctxo, baseo, map,
                                            ln1_g + l * D, ln1_b + l * D,
                                            w1T, ff1_b + l * FF,
                                            w2T, ff2_b + l * D,
                                            ln2_g + l * D, ln2_b + l * D, h);
  }

  k_head<<<B, D, 0, stream>>>(h, head_g, head_bb, head_w, head_wb, out);
}